// Round 7
// baseline (366.833 us; speedup 1.0000x reference)
//
#include <hip/hip_runtime.h>
#include <cfloat>
#include <climits>
#include <math.h>

#define BN 16
#define QN 4096
#define GN 256
#define CN 80
#define NPART 128          // row parts in k_main (32 rows each)
#define RPP (QN / NPART)   // 32
#define NPRM 23            // column params

// k_pre sub-grid sizes
#define NZ_BLK 1161        // zero: ceil(296968/256)
#define NC_BLK 2048        // class: 16 b x 64 iblk x 2 half
#define NF_BLK 1024        // fg: 16 itile x 16 b x 4 part

typedef unsigned long long u64;

__device__ __forceinline__ bool lexLessF(float a, int ia, float b, int ib) {
    return (a < b) || (a == b && ia < ib);
}
// IEEE order-isomorphic u32 key (no NaNs in this data)
__device__ __forceinline__ unsigned int fkey(float f) {
    unsigned int b = __float_as_uint(f);
    return b ^ ((b >> 31) ? 0xFFFFFFFFu : 0x80000000u);
}
__device__ __forceinline__ float funkey(unsigned int k) {
    unsigned int b = k ^ ((k >> 31) ? 0x80000000u : 0xFFFFFFFFu);
    return __uint_as_float(b);
}

// ---------------- mega pre-kernel: zero | class | fg ----------------
__global__ __launch_bounds__(256) void k_pre(const float* __restrict__ logits,
                                             const float* __restrict__ gtb,
                                             const float* __restrict__ gtt,
                                             const float* __restrict__ gtr,
                                             const float* __restrict__ imgt,
                                             const float* __restrict__ pb,
                                             u64* __restrict__ zbase, int zn,
                                             float* __restrict__ cclsT,
                                             float* __restrict__ prmT,
                                             unsigned char* __restrict__ fgp) {
#pragma clang fp contract(off)
    const int blk = blockIdx.x;
    if (blk < NZ_BLK) {
        int i = blk * 256 + threadIdx.x;
        if (i < zn) zbase[i] = 0ull;
        return;
    }
    if (blk < NZ_BLK + NC_BLK) {
        // ---- class: ccls[b][i][c] (10 classes/thread, float2) + prm ----
        const int bid = blk - NZ_BLK;
        const int b = bid >> 7;
        const int rem = bid & 127;
        const int iblk = rem >> 1, h = rem & 1;
        const int lane = threadIdx.x & 63, cg_ = threadIdx.x >> 6;
        const int i = iblk * 64 + lane;
        const int c0 = h * 40 + cg_ * 10;
        const float* lrow = logits + ((size_t)(b * QN + i)) * CN + c0;
        float* orow = cclsT + ((size_t)(b * QN + i)) * CN + c0;
#pragma unroll
        for (int q = 0; q < 5; q++) {
            const float2 xv = *reinterpret_cast<const float2*>(lrow + q * 2);
            float xs[2] = {xv.x, xv.y};
            float os[2];
#pragma unroll
            for (int u = 0; u < 2; u++) {
                float x = xs[u];
                float e = (float)exp(-(double)x);
                float pr = 1.0f / (1.0f + e);
                float om = 1.0f - pr;
                float lneg = (float)log((double)(om + 1e-8f));
                float lpos = (float)log((double)(pr + 1e-8f));
                float neg = (0.75f * (pr * pr)) * (-lneg);
                float pos = (0.25f * (om * om)) * (-lpos);
                os[u] = pos - neg;
            }
            *reinterpret_cast<float2*>(orow + q * 2) = make_float2(os[0], os[1]);
        }
        if (rem == 0) {
            const int j = threadIdx.x;
            const float* g = gtb + ((size_t)(b * GN + j)) * 4;
            const float g0 = g[0], g1 = g[1], g2 = g[2], g3 = g[3];
            const float* it = imgt + ((size_t)(b * GN + j)) * 4;
            float* P = prmT + (size_t)b * NPRM * GN;
            P[0 * GN + j] = g0; P[1 * GN + j] = g1; P[2 * GN + j] = g2; P[3 * GN + j] = g3;
            P[4 * GN + j] = g0 / it[0]; P[5 * GN + j] = g1 / it[1];
            P[6 * GN + j] = g2 / it[2]; P[7 * GN + j] = g3 / it[3];
            P[8 * GN + j] = gtt[(b * GN + j) * 3 + 0]; P[9 * GN + j] = gtt[(b * GN + j) * 3 + 1];
            P[10 * GN + j] = gtt[(b * GN + j) * 3 + 2];
            P[11 * GN + j] = gtr[(b * GN + j) * 3 + 0]; P[12 * GN + j] = gtr[(b * GN + j) * 3 + 1];
            P[13 * GN + j] = gtr[(b * GN + j) * 3 + 2];
            P[14 * GN + j] = (g2 - g0) * (g3 - g1);   // ga
            float gcx = (g0 + g2) * 0.5f, gcy = (g1 + g3) * 0.5f;
            float gw = g2 - g0, gh = g3 - g1;
            float X0 = gcx - gw * 0.5f, Y0 = gcy - gh * 0.5f;
            float X1 = gcx + gw * 0.5f, Y1 = gcy + gh * 0.5f;
            float Wd = X1 - X0, Hd = Y1 - Y0;
            P[15 * GN + j] = X0; P[16 * GN + j] = Y0; P[17 * GN + j] = X1; P[18 * GN + j] = Y1;
            P[19 * GN + j] = gcx - 2.5f * Wd; P[20 * GN + j] = gcx + 2.5f * Wd;
            P[21 * GN + j] = gcy - 2.5f * Hd; P[22 * GN + j] = gcy + 2.5f * Hd;
        }
        return;
    }
    // ---- fg: 4-way j-split, float4 LDS ----
    {
        const int bid = blk - NZ_BLK - NC_BLK;       // itile(16) x b(16) x part(4)
        const int itile = bid >> 6;
        const int b = (bid >> 2) & 15;
        const int part = bid & 3;
        const int i = itile * 256 + threadIdx.x;
        __shared__ float4 sA[64], sB[64];
        if (threadIdx.x < 64) {
            const int j = part * 64 + threadIdx.x;
            const float* g = gtb + ((size_t)(b * GN + j)) * 4;
            float g0 = g[0], g1 = g[1], g2 = g[2], g3 = g[3];
            float gcx = (g0 + g2) * 0.5f, gcy = (g1 + g3) * 0.5f;
            float gw = g2 - g0, gh = g3 - g1;
            float x0 = gcx - gw * 0.5f, y0 = gcy - gh * 0.5f;
            float x1 = gcx + gw * 0.5f, y1 = gcy + gh * 0.5f;
            float w = x1 - x0, h2 = y1 - y0;
            sA[threadIdx.x] = make_float4(x0, y0, x1, y1);
            sB[threadIdx.x] = make_float4(gcx - 2.5f * w, gcx + 2.5f * w,
                                          gcy - 2.5f * h2, gcy + 2.5f * h2);
        }
        __syncthreads();
        const float4 bb = *reinterpret_cast<const float4*>(pb + ((size_t)(b * QN + i)) * 4);
        float ax = (bb.x + bb.z) * 0.5f, ay = (bb.y + bb.w) * 0.5f;
        bool anyib = false, anyic = false;
#pragma unroll 8
        for (int j = 0; j < 64; j++) {
            const float4 A = sA[j], B = sB[j];
            bool ib = (ax > A.x) && (ax < A.z) && (ay > A.y) && (ay < A.w);
            bool ic = (ax > B.x) && (ax < B.y) && (ay > B.z) && (ay < B.w);
            anyib |= ib; anyic |= ic;
        }
        fgp[((size_t)b * QN + i) * 4 + part] = (anyib || anyic) ? 1 : 0;
    }
}

// ---------------- fused cost + selection: column-per-thread, u64 keys ----------------
// Output interface: rec[col][part] = 64B record {5x u64 key, 5x f32 iou, pad}
__global__ __launch_bounds__(256) void k_main(
    const float* __restrict__ cclsT, const int* __restrict__ labels,
    const float* __restrict__ prmT,
    const float* __restrict__ pboxes, const float* __restrict__ pposes,
    const float* __restrict__ img, const unsigned int* __restrict__ fgw,
    float* __restrict__ costT,
    u64* __restrict__ rec) {
#pragma clang fp contract(off)
    const int j = threadIdx.x;
    const int b = blockIdx.x >> 7;
    const int part = blockIdx.x & 127;
    const int i0 = part * RPP;

    __shared__ float4 Rsh[RPP][5];
    if (threadIdx.x < RPP) {
        const int i = i0 + threadIdx.x;
        const float im0 = img[b * 4 + 0], im1 = img[b * 4 + 1];
        const float im2 = img[b * 4 + 2], im3 = img[b * 4 + 3];
        const float4 bx = *reinterpret_cast<const float4*>(pboxes + ((size_t)(b * QN + i)) * 4);
        const float b0 = bx.x, b1 = bx.y, b2 = bx.z, b3 = bx.w;
        const float2* pp2 = reinterpret_cast<const float2*>(pposes + ((size_t)(b * QN + i)) * 6);
        const float2 q0 = pp2[0], q1 = pp2[1], q2 = pp2[2];
        const float fgadd = fgw[(size_t)b * QN + i] ? 0.0f : 10000.0f;
        const float bn0 = b0 / im0, bn1 = b1 / im1, bn2 = b2 / im2, bn3 = b3 / im3;
        const float a1 = (b2 - b0) * (b3 - b1);
        const float ax = (b0 + b2) * 0.5f, ay = (b1 + b3) * 0.5f;
        Rsh[threadIdx.x][0] = make_float4(b0, b1, b2, b3);
        Rsh[threadIdx.x][1] = make_float4(bn0, bn1, bn2, bn3);
        Rsh[threadIdx.x][2] = make_float4(ax, ay, a1, fgadd);
        Rsh[threadIdx.x][3] = make_float4(q0.x, q0.y, q1.x, q1.y);
        Rsh[threadIdx.x][4] = make_float4(q2.x, q2.y, 0.0f, 0.0f);
    }

    const float* P = prmT + (size_t)b * NPRM * GN;
    const float g0 = P[0 * GN + j], g1 = P[1 * GN + j], g2 = P[2 * GN + j], g3 = P[3 * GN + j];
    const float gn0 = P[4 * GN + j], gn1 = P[5 * GN + j], gn2 = P[6 * GN + j], gn3 = P[7 * GN + j];
    const float t0 = P[8 * GN + j], t1 = P[9 * GN + j], t2 = P[10 * GN + j];
    const float r0 = P[11 * GN + j], r1 = P[12 * GN + j], r2 = P[13 * GN + j];
    const float ga = P[14 * GN + j];
    const float X0 = P[15 * GN + j], Y0 = P[16 * GN + j], X1 = P[17 * GN + j], Y1 = P[18 * GN + j];
    const float LOX = P[19 * GN + j], HIX = P[20 * GN + j], LOY = P[21 * GN + j], HIY = P[22 * GN + j];
    const int lab = labels[b * GN + j];

    const float* CB = cclsT + ((size_t)(b * QN) + i0) * CN;     // uniform base + lab
    float* CT = costT + ((size_t)(b * QN) + i0) * GN + j;

    u64 ck[5]; float iv[5];
#pragma unroll
    for (int k = 0; k < 5; k++) { ck[k] = ~0ull; iv[k] = -1.0f; }

    __syncthreads();

    for (int r = 0; r < RPP; r++) {
        const int i = i0 + r;
        const float4 R0 = Rsh[r][0];
        const float4 R1 = Rsh[r][1];
        const float4 R2 = Rsh[r][2];
        const float4 R3 = Rsh[r][3];
        const float4 R4 = Rsh[r][4];
        const float b0 = R0.x, b1 = R0.y, b2 = R0.z, b3 = R0.w;
        const float bn0 = R1.x, bn1 = R1.y, bn2 = R1.z, bn3 = R1.w;
        const float ax = R2.x, ay = R2.y, a1 = R2.z, fgadd = R2.w;
        const float p0 = R3.x, p1 = R3.y, p2 = R3.z, p3 = R3.w;
        const float p4 = R4.x, p5 = R4.y;
        const float cc = CB[r * CN + lab];

        // iou / giou (f32, reference op order)
        float ltx = fmaxf(b0, g0), lty = fmaxf(b1, g1);
        float rbx = fminf(b2, g2), rby = fminf(b3, g3);
        float w = fmaxf(rbx - ltx, 0.0f), h = fmaxf(rby - lty, 0.0f);
        float inter = w * h;
        float uni = (a1 + ga) - inter;
        float iou = inter / uni;
        float eltx = fminf(b0, g0), elty = fminf(b1, g1);
        float erbx = fmaxf(b2, g2), erby = fmaxf(b3, g3);
        float ew = fmaxf(erbx - eltx, 0.0f), eh = fmaxf(erby - elty, 0.0f);
        float earea = ew * eh;
        float giou = iou - (earea - uni) / earea;

        // normalized bbox L1 (sequential f32)
        float cb = fabsf(bn0 - gn0);
        cb = cb + fabsf(bn1 - gn1);
        cb = cb + fabsf(bn2 - gn2);
        cb = cb + fabsf(bn3 - gn3);
        // pose L1
        float ct = fabsf(p0 - t0); ct = ct + fabsf(p1 - t1); ct = ct + fabsf(p2 - t2);
        float cr = fabsf(p3 - r0); cr = cr + fabsf(p4 - r1); cr = cr + fabsf(p5 - r2);
        // both
        bool ib = (ax > X0) && (ax < X1) && (ay > Y0) && (ay < Y1);
        bool ic = (ax > LOX) && (ax < HIX) && (ay > LOY) && (ay < HIY);
        bool nb = !(ib && ic);

        float d = 5.0f * cb;
        d = d + 2.0f * cc;
        d = d + 2.0f * (-giou);
        d = d + (nb ? 100.0f : 0.0f);
        d = d + ct;
        d = d + cr;
        d = d + fgadd;

        CT[(size_t)r * GN] = d;

        // bottom-5 via u64 key cascade (order-isomorphic to (cost,i) lex)
        u64 key = ((u64)fkey(d) << 32) | (unsigned int)i;
        if (key < ck[4]) {
#pragma unroll
            for (int k = 0; k < 5; k++) {
                u64 mn = key < ck[k] ? key : ck[k];
                u64 mx = key < ck[k] ? ck[k] : key;
                ck[k] = mn; key = mx;
            }
        }
        // top-5 iou via max/min network
        if (iou > iv[4]) {
            float fv = iou;
#pragma unroll
            for (int k = 0; k < 5; k++) {
                float mx = fmaxf(fv, iv[k]);
                fv = fminf(fv, iv[k]);
                iv[k] = mx;
            }
        }
    }

    // pack one 64B record and store as 4x16B (full-line write)
    const int col = b * GN + j;
    u64 buf[8];
#pragma unroll
    for (int k = 0; k < 5; k++) buf[k] = ck[k];
    float* bf = (float*)(buf + 5);
#pragma unroll
    for (int k = 0; k < 5; k++) bf[k] = iv[k];
    bf[5] = 0.0f;                                   // pad -> full 64B line
    ulonglong2* dst = (ulonglong2*)(rec + (((size_t)col * NPART) + part) * 8);
    const ulonglong2* src = (const ulonglong2*)buf;
    dst[0] = src[0]; dst[1] = src[1]; dst[2] = src[2]; dst[3] = src[3];
}

// ---------------- merge parts (wave butterfly), dk, rowmask, rowcnt, amin init ----------------
__global__ __launch_bounds__(256) void k_dk(const u64* __restrict__ rec,
                                            float* __restrict__ candcv, int* __restrict__ candci,
                                            int* __restrict__ dkArr, u64* __restrict__ rowmask,
                                            u64* __restrict__ amin, int* __restrict__ rowcnt) {
#pragma clang fp contract(off)
    const int lane = threadIdx.x & 63;
    const int colIdx = blockIdx.x * 4 + (threadIdx.x >> 6);   // 4 waves/block
    const int b = colIdx >> 8, j = colIdx & 255;
    // rec[col][part]: wave reads parts lane and lane+64 -> two contiguous 4KiB spans
    const u64* R0 = rec + (((size_t)colIdx * NPART) + lane) * 8;
    const u64* R1 = R0 + 64 * 8;
    u64 rv[5]; float fr[5];
    const float* F0 = (const float*)(R0 + 5);
#pragma unroll
    for (int k = 0; k < 5; k++) { rv[k] = R0[k]; fr[k] = F0[k]; }
    const float* F1 = (const float*)(R1 + 5);
#pragma unroll
    for (int m = 0; m < 5; m++) {
        u64 key = R1[m];
        if (key < rv[4]) {
#pragma unroll
            for (int k = 0; k < 5; k++) {
                u64 mn = key < rv[k] ? key : rv[k];
                u64 mx = key < rv[k] ? rv[k] : key;
                rv[k] = mn; key = mx;
            }
        }
        float fv = F1[m];
        if (fv > fr[4]) {
#pragma unroll
            for (int k = 0; k < 5; k++) {
                float mx = fmaxf(fv, fr[k]);
                fv = fminf(fv, fr[k]);
                fr[k] = mx;
            }
        }
    }
    for (int off = 1; off < 64; off <<= 1) {
        u64 ov[5]; float of[5];
#pragma unroll
        for (int m = 0; m < 5; m++) {
            ov[m] = __shfl_xor(rv[m], off, 64);
            of[m] = __shfl_xor(fr[m], off, 64);
        }
#pragma unroll
        for (int m = 0; m < 5; m++) {
            u64 key = ov[m];
            if (key < rv[4]) {
#pragma unroll
                for (int k = 0; k < 5; k++) {
                    u64 mn = key < rv[k] ? key : rv[k];
                    u64 mx = key < rv[k] ? rv[k] : key;
                    rv[k] = mn; key = mx;
                }
            }
            float fv = of[m];
            if (fv > fr[4]) {
#pragma unroll
                for (int k = 0; k < 5; k++) {
                    float mx = fmaxf(fv, fr[k]);
                    fv = fminf(fv, fr[k]);
                    fr[k] = mx;
                }
            }
        }
    }

    if (lane == 0) {
        float sum = ((((fr[0] + fr[1]) + fr[2]) + fr[3]) + fr[4]);  // desc order, sequential
        int dk = (int)sum;
        if (dk < 1) dk = 1;
        if (dk > 5) dk = 5;
        dkArr[colIdx] = dk;
        amin[colIdx] = ~0ull;
#pragma unroll
        for (int k = 0; k < 5; k++) {
            candcv[(size_t)colIdx * 5 + k] = funkey((unsigned int)(rv[k] >> 32));
            candci[(size_t)colIdx * 5 + k] = (int)(unsigned int)(rv[k] & 0xFFFFFFFFull);
        }
        for (int k = 0; k < dk; k++) {
            int i = (int)(unsigned int)(rv[k] & 0xFFFFFFFFull);
            atomicOr(&rowmask[((size_t)(b * QN + i)) * 4 + (j >> 6)], 1ull << (j & 63));
            atomicAdd(&rowcnt[b * QN + i], 1);
        }
    }
}

// ---------------- fused: detect+wave-parallel stalefix (blocks 0..255) | candidate-assign ----
// Racy-monotone colcnt semantics as the verified k_fix: assign's spurious amin writes for
// columns stalefix matches are discarded by the final colcnt read in k_outA.
__global__ __launch_bounds__(256) void k_fix4(const float* __restrict__ costT,
                                              u64* __restrict__ rowmask,
                                              int* __restrict__ colcnt,
                                              int* __restrict__ staleCount,
                                              int* __restrict__ staleList,
                                              int* __restrict__ fixBj,
                                              const int* __restrict__ rowcnt,
                                              const float* __restrict__ candcv,
                                              const int* __restrict__ candci,
                                              u64* __restrict__ amin) {
    if (blockIdx.x < 256) {
        // ---- row side: per-thread detect, wave-cooperative fix ----
        const int b = blockIdx.x >> 4;
        const int i = (blockIdx.x & 15) * 256 + threadIdx.x;
        const int lane = threadIdx.x & 63;
        const int cnt = rowcnt[b * QN + i];
        int e = -1;
        if (cnt > 1) {
            e = atomicAdd(staleCount, 1);
            staleList[e] = (b << 12) | i;
        } else if (cnt == 1) {
            const u64* rm = rowmask + ((size_t)(b * QN + i)) * 4;
            u64 w0 = rm[0], w1 = rm[1], w2 = rm[2], w3 = rm[3];
            u64 w; int base;
            if (w0) { w = w0; base = 0; }
            else if (w1) { w = w1; base = 64; }
            else if (w2) { w = w2; base = 128; }
            else { w = w3; base = 192; }
            int jj = base + (__ffsll((long long)w) - 1);
            atomicAdd(&colcnt[b * GN + jj], 1);
        }
        // wave-cooperative fix of flagged rows (one row at a time, 64-lane scan)
        u64 bal = __ballot(cnt > 1);
        while (bal) {
            const int L = __ffsll((long long)bal) - 1;
            bal &= bal - 1;
            const int iL = (i & ~63) | L;
            const int eL = __shfl(e, L, 64);
            const float* cb = costT + ((size_t)(b * QN) + iL) * GN;   // contiguous row
            float best = FLT_MAX; int bj = GN;
            for (int k = 0; k < GN; k += 64) {
                int jj = k + lane;
                float v = cb[jj];
                if (lexLessF(v, jj, best, bj)) { best = v; bj = jj; }
            }
            for (int off = 32; off > 0; off >>= 1) {
                float ov = __shfl_down(best, off, 64);
                int oj = __shfl_down(bj, off, 64);
                if (lexLessF(ov, oj, best, bj)) { best = ov; bj = oj; }
            }
            if (lane == 0) {
                u64* rm = rowmask + ((size_t)(b * QN + iL)) * 4;
                rm[0] = ((bj >> 6) == 0) ? (1ull << (bj & 63)) : 0ull;
                rm[1] = ((bj >> 6) == 1) ? (1ull << (bj & 63)) : 0ull;
                rm[2] = ((bj >> 6) == 2) ? (1ull << (bj & 63)) : 0ull;
                rm[3] = ((bj >> 6) == 3) ? (1ull << (bj & 63)) : 0ull;
                atomicAdd(&colcnt[b * GN + bj], 1);
                fixBj[eL] = bj;
            }
        }
        return;
    }

    // ---- candidate-based assign: 16 blocks, 1 thread/column ----
    __shared__ int fbList[256];
    __shared__ int fbCnt;
    __shared__ u64 red[256];

    const int b = blockIdx.x - 256;
    const int j = threadIdx.x;
    const int col = b * GN + j;
    if (threadIdx.x == 0) fbCnt = 0;
    __syncthreads();

    if (colcnt[col] == 0) {   // racy read; monotone => spurious assigns discarded later
        // first unmatched candidate in sorted bottom-5 == argmin over unmatched rows,
        // since any row outside the bottom-5 has key >= all listed keys.
        bool found = false;
        u64 best = ~0ull;
#pragma unroll
        for (int k = 0; k < 5; k++) {
            if (!found) {
                int i = candci[(size_t)col * 5 + k];
                if (rowcnt[b * QN + i] == 0) {
                    best = ((u64)fkey(candcv[(size_t)col * 5 + k]) << 32) | (unsigned int)i;
                    found = true;
                }
            }
        }
        if (found) {
            amin[col] = best;
        } else {
            int e = atomicAdd(&fbCnt, 1);
            fbList[e] = j;
        }
    }
    __syncthreads();

    // rare fallback: all 5 candidates matched -> block-parallel column scan over unmatched rows
    const int nfb = fbCnt;
    for (int c = 0; c < nfb; c++) {
        const int jc = fbList[c];
        const int t = threadIdx.x;
        const float* C = costT + ((size_t)(b * QN)) * GN + jc;
        u64 best = ~0ull;
        for (int r = t; r < QN; r += 256) {
            if (rowcnt[b * QN + r] == 0) {
                float v = C[(size_t)r * GN];
                u64 key = ((u64)fkey(v) << 32) | (unsigned int)r;
                best = key < best ? key : best;
            }
        }
        red[t] = best;
        __syncthreads();
        for (int s = 128; s > 0; s >>= 1) {
            if (t < s) { u64 o = red[t + s]; if (o < red[t]) red[t] = o; }
            __syncthreads();
        }
        if (t == 0) amin[b * GN + jc] = red[0];
        __syncthreads();
    }
}

// ---------------- fused: assignfix+outcols (blocks 0..15) | outrows (blocks 16..271) ----------
// Cross-block communication is exclusively via device-scope atomics (rowmask atomicOr + done
// counter) -> coherent at the LLC across XCDs, no L2 writeback needed. All 272 blocks are
// co-resident (272 << capacity at this register/LDS footprint), producers never wait.
__global__ __launch_bounds__(256) void k_outA(const float* __restrict__ costT,
                                              u64* __restrict__ rowmask,
                                              const int* __restrict__ colcnt,
                                              const float* __restrict__ candcv,
                                              const int* __restrict__ candci,
                                              const int* __restrict__ dkArr,
                                              const int* __restrict__ staleCount,
                                              const int* __restrict__ staleList,
                                              const int* __restrict__ fixBj,
                                              const u64* __restrict__ amin,
                                              int* __restrict__ done,
                                              int* __restrict__ out) {
    if (blockIdx.x < BN) {
        // ---- assignfix for batch b, then outcols for batch b ----
        const int b = blockIdx.x;
        const int j = threadIdx.x;
        const int col = b * GN + j;
        int a;
        if (colcnt[col] != 0) {
            a = -1;
        } else {
            u64 key = amin[col];
            int r = (int)(unsigned int)(key & 0xFFFFFFFFull);
            a = r;
            atomicOr(&rowmask[((size_t)(b * QN + r)) * 4 + (j >> 6)], 1ull << (j & 63));
        }
        __syncthreads();
        __threadfence();
        if (threadIdx.x == 0) atomicAdd(done, 1);   // release: ORs complete before signal

        // outcols: only depends on batch-b rowmask (k_dk/k_fix4 = prior kernels; assignfix
        // bits for batch b were set by THIS block -> visible after syncthreads)
        int* o = out + (size_t)2 * BN * QN + col;
        if (a >= 0) { *o = a; return; }
        const u64 bit = 1ull << (j & 63);
        const int w = j >> 6;
        float best = FLT_MAX; int bi = INT_MAX;
        const int dk = dkArr[col];
        for (int k = 0; k < 5; k++) {
            if (k < dk) {
                int i = candci[(size_t)col * 5 + k];
                if (rowmask[((size_t)(b * QN + i)) * 4 + w] & bit) {
                    float pv = candcv[(size_t)col * 5 + k] + 100000.0f;
                    if (lexLessF(pv, i, best, bi)) { best = pv; bi = i; }
                }
            }
        }
        const int n = *staleCount;
        for (int e = 0; e < n; e++) {
            int pk = staleList[e];
            int eb = pk >> 12, ei = pk & 4095;
            if (eb == b && fixBj[e] == j) {
                float pv = costT[((size_t)(b * QN) + ei) * GN + j] + 100000.0f;
                if (lexLessF(pv, ei, best, bi)) { best = pv; bi = ei; }
            }
        }
        *o = (bi == INT_MAX) ? 0 : bi;
        return;
    }
    // ---- outrows: wait for all 16 assignfix blocks, then read rowmask ----
    {
        const int blk = blockIdx.x - BN;
        const int b = blk >> 4;
        const int i = (blk & 15) * 256 + threadIdx.x;
        if (threadIdx.x == 0) {
            while (atomicAdd(done, 0) < BN) { __builtin_amdgcn_s_sleep(8); }
        }
        __syncthreads();
        __threadfence();
        const u64* rm = rowmask + ((size_t)(b * QN + i)) * 4;
        u64 w0 = rm[0], w1 = rm[1], w2 = rm[2], w3 = rm[3];
        int sel = (w0 | w1 | w2 | w3) ? 1 : 0;
        int g = 0;
        if (w0) g = __ffsll((long long)w0) - 1;
        else if (w1) g = 64 + __ffsll((long long)w1) - 1;
        else if (w2) g = 128 + __ffsll((long long)w2) - 1;
        else if (w3) g = 192 + __ffsll((long long)w3) - 1;
        out[(size_t)b * QN + i] = sel;
        out[(size_t)BN * QN + (size_t)b * QN + i] = g;
    }
}

extern "C" void kernel_launch(void* const* d_in, const int* in_sizes, int n_in,
                              void* d_out, int out_size, void* d_ws, size_t ws_size,
                              hipStream_t stream) {
    const float* logits = (const float*)d_in[0];
    const float* pboxes = (const float*)d_in[1];
    const float* pposes = (const float*)d_in[2];
    const int* labels = (const int*)d_in[3];
    const float* gtb = (const float*)d_in[4];
    const float* gtt = (const float*)d_in[5];
    const float* gtr = (const float*)d_in[6];
    const float* img = (const float*)d_in[7];
    const float* imgt = (const float*)d_in[8];
    int* out = (int*)d_out;

    char* p = (char*)d_ws;
    float* costT = (float*)p;            p += (size_t)BN * QN * GN * 4;        // 64 MiB
    float* cclsT = (float*)p;            p += (size_t)BN * QN * CN * 4;        // 20 MiB
    u64* rec = (u64*)p;                  p += (size_t)BN * GN * NPART * 64;    // 32 MiB (64B/record)
    // ---- zero region: rowmask | colcnt | staleCount+done | rowcnt (contiguous) ----
    u64* rowmask = (u64*)p;              size_t rb = (size_t)BN * QN * 4 * 8; p += rb;  // 2 MiB
    int* colcnt = (int*)p;               p += (size_t)BN * GN * 4;             // 16 KiB
    int* staleCount = (int*)p;           int* done = staleCount + 1; p += 64;
    int* rowcnt = (int*)p;               p += (size_t)BN * QN * 4;             // 256 KiB
    // ---- end zero region ----
    int* staleList = (int*)p;            p += (size_t)BN * QN * 4;             // 256 KiB
    int* fixBj = (int*)p;                p += (size_t)BN * QN * 4;             // 256 KiB
    unsigned char* fgp = (unsigned char*)p; p += (size_t)BN * QN * 4;          // 256 KiB
    float* prmT = (float*)p;             p += (size_t)BN * NPRM * GN * 4;      // 376 KiB
    float* candcv = (float*)p;           p += (size_t)BN * GN * 5 * 4;         // 80 KiB
    int* candci = (int*)p;               p += (size_t)BN * GN * 5 * 4;         // 80 KiB
    int* dkArr = (int*)p;                p += (size_t)BN * GN * 4;             // 16 KiB
    u64* amin = (u64*)p;                 p += (size_t)BN * GN * 8;             // 32 KiB

    // zero region size in u64: rowmask(2MiB) + colcnt(16KiB) + 64B + rowcnt(256KiB)
    int zn = (int)((rb + (size_t)BN * GN * 4 + 64 + (size_t)BN * QN * 4) / 8);  // = 296968

    k_pre<<<NZ_BLK + NC_BLK + NF_BLK, 256, 0, stream>>>(logits, gtb, gtt, gtr, imgt, pboxes,
                                                        rowmask, zn, cclsT, prmT, fgp);
    k_main<<<BN * NPART, 256, 0, stream>>>(cclsT, labels, prmT, pboxes, pposes, img,
                                           (const unsigned int*)fgp, costT, rec);
    k_dk<<<BN * GN / 4, 256, 0, stream>>>(rec, candcv, candci, dkArr, rowmask, amin, rowcnt);
    k_fix4<<<256 + BN, 256, 0, stream>>>(costT, rowmask, colcnt, staleCount, staleList,
                                         fixBj, rowcnt, candcv, candci, amin);
    k_outA<<<BN + 256, 256, 0, stream>>>(costT, rowmask, colcnt, candcv, candci, dkArr,
                                         staleCount, staleList, fixBj, amin, done, out);
}

// Round 9
// 271.198 us; speedup vs baseline: 1.3526x; 1.3526x over previous
//
#include <hip/hip_runtime.h>
#include <cfloat>
#include <climits>
#include <math.h>

#define BN 16
#define QN 4096
#define GN 256
#define CN 80
#define NPART 128          // row parts in k_main (32 rows each)
#define RPP (QN / NPART)   // 32
#define NPRM 23            // column params

// k_pre sub-grid sizes
#define NZ_BLK 1161        // zero: ceil(296968/256)
#define NC_BLK 2048        // class: 16 b x 64 iblk x 2 half
#define NF_BLK 1024        // fg: 16 itile x 16 b x 4 part

typedef unsigned long long u64;

__device__ __forceinline__ bool lexLessF(float a, int ia, float b, int ib) {
    return (a < b) || (a == b && ia < ib);
}
// IEEE order-isomorphic u32 key (no NaNs in this data)
__device__ __forceinline__ unsigned int fkey(float f) {
    unsigned int b = __float_as_uint(f);
    return b ^ ((b >> 31) ? 0xFFFFFFFFu : 0x80000000u);
}
__device__ __forceinline__ float funkey(unsigned int k) {
    unsigned int b = k ^ ((k >> 31) ? 0x80000000u : 0xFFFFFFFFu);
    return __uint_as_float(b);
}

// ---------------- mega pre-kernel: zero | class | fg ----------------
__global__ __launch_bounds__(256) void k_pre(const float* __restrict__ logits,
                                             const float* __restrict__ gtb,
                                             const float* __restrict__ gtt,
                                             const float* __restrict__ gtr,
                                             const float* __restrict__ imgt,
                                             const float* __restrict__ pb,
                                             u64* __restrict__ zbase, int zn,
                                             float* __restrict__ cclsT,
                                             float* __restrict__ prmT,
                                             unsigned char* __restrict__ fgp) {
#pragma clang fp contract(off)
    const int blk = blockIdx.x;
    if (blk < NZ_BLK) {
        int i = blk * 256 + threadIdx.x;
        if (i < zn) zbase[i] = 0ull;
        return;
    }
    if (blk < NZ_BLK + NC_BLK) {
        // ---- class: ccls[b][i][c] (10 classes/thread, float2) + prm ----
        const int bid = blk - NZ_BLK;
        const int b = bid >> 7;
        const int rem = bid & 127;
        const int iblk = rem >> 1, h = rem & 1;
        const int lane = threadIdx.x & 63, cg_ = threadIdx.x >> 6;
        const int i = iblk * 64 + lane;
        const int c0 = h * 40 + cg_ * 10;
        const float* lrow = logits + ((size_t)(b * QN + i)) * CN + c0;
        float* orow = cclsT + ((size_t)(b * QN + i)) * CN + c0;
#pragma unroll
        for (int q = 0; q < 5; q++) {
            const float2 xv = *reinterpret_cast<const float2*>(lrow + q * 2);
            float xs[2] = {xv.x, xv.y};
            float os[2];
#pragma unroll
            for (int u = 0; u < 2; u++) {
                float x = xs[u];
                float e = (float)exp(-(double)x);
                float pr = 1.0f / (1.0f + e);
                float om = 1.0f - pr;
                float lneg = (float)log((double)(om + 1e-8f));
                float lpos = (float)log((double)(pr + 1e-8f));
                float neg = (0.75f * (pr * pr)) * (-lneg);
                float pos = (0.25f * (om * om)) * (-lpos);
                os[u] = pos - neg;
            }
            *reinterpret_cast<float2*>(orow + q * 2) = make_float2(os[0], os[1]);
        }
        if (rem == 0) {
            const int j = threadIdx.x;
            const float* g = gtb + ((size_t)(b * GN + j)) * 4;
            const float g0 = g[0], g1 = g[1], g2 = g[2], g3 = g[3];
            const float* it = imgt + ((size_t)(b * GN + j)) * 4;
            float* P = prmT + (size_t)b * NPRM * GN;
            P[0 * GN + j] = g0; P[1 * GN + j] = g1; P[2 * GN + j] = g2; P[3 * GN + j] = g3;
            P[4 * GN + j] = g0 / it[0]; P[5 * GN + j] = g1 / it[1];
            P[6 * GN + j] = g2 / it[2]; P[7 * GN + j] = g3 / it[3];
            P[8 * GN + j] = gtt[(b * GN + j) * 3 + 0]; P[9 * GN + j] = gtt[(b * GN + j) * 3 + 1];
            P[10 * GN + j] = gtt[(b * GN + j) * 3 + 2];
            P[11 * GN + j] = gtr[(b * GN + j) * 3 + 0]; P[12 * GN + j] = gtr[(b * GN + j) * 3 + 1];
            P[13 * GN + j] = gtr[(b * GN + j) * 3 + 2];
            P[14 * GN + j] = (g2 - g0) * (g3 - g1);   // ga
            float gcx = (g0 + g2) * 0.5f, gcy = (g1 + g3) * 0.5f;
            float gw = g2 - g0, gh = g3 - g1;
            float X0 = gcx - gw * 0.5f, Y0 = gcy - gh * 0.5f;
            float X1 = gcx + gw * 0.5f, Y1 = gcy + gh * 0.5f;
            float Wd = X1 - X0, Hd = Y1 - Y0;
            P[15 * GN + j] = X0; P[16 * GN + j] = Y0; P[17 * GN + j] = X1; P[18 * GN + j] = Y1;
            P[19 * GN + j] = gcx - 2.5f * Wd; P[20 * GN + j] = gcx + 2.5f * Wd;
            P[21 * GN + j] = gcy - 2.5f * Hd; P[22 * GN + j] = gcy + 2.5f * Hd;
        }
        return;
    }
    // ---- fg: 4-way j-split, float4 LDS ----
    {
        const int bid = blk - NZ_BLK - NC_BLK;       // itile(16) x b(16) x part(4)
        const int itile = bid >> 6;
        const int b = (bid >> 2) & 15;
        const int part = bid & 3;
        const int i = itile * 256 + threadIdx.x;
        __shared__ float4 sA[64], sB[64];
        if (threadIdx.x < 64) {
            const int j = part * 64 + threadIdx.x;
            const float* g = gtb + ((size_t)(b * GN + j)) * 4;
            float g0 = g[0], g1 = g[1], g2 = g[2], g3 = g[3];
            float gcx = (g0 + g2) * 0.5f, gcy = (g1 + g3) * 0.5f;
            float gw = g2 - g0, gh = g3 - g1;
            float x0 = gcx - gw * 0.5f, y0 = gcy - gh * 0.5f;
            float x1 = gcx + gw * 0.5f, y1 = gcy + gh * 0.5f;
            float w = x1 - x0, h2 = y1 - y0;
            sA[threadIdx.x] = make_float4(x0, y0, x1, y1);
            sB[threadIdx.x] = make_float4(gcx - 2.5f * w, gcx + 2.5f * w,
                                          gcy - 2.5f * h2, gcy + 2.5f * h2);
        }
        __syncthreads();
        const float4 bb = *reinterpret_cast<const float4*>(pb + ((size_t)(b * QN + i)) * 4);
        float ax = (bb.x + bb.z) * 0.5f, ay = (bb.y + bb.w) * 0.5f;
        bool anyib = false, anyic = false;
#pragma unroll 8
        for (int j = 0; j < 64; j++) {
            const float4 A = sA[j], B = sB[j];
            bool ib = (ax > A.x) && (ax < A.z) && (ay > A.y) && (ay < A.w);
            bool ic = (ax > B.x) && (ax < B.y) && (ay > B.z) && (ay < B.w);
            anyib |= ib; anyic |= ic;
        }
        fgp[((size_t)b * QN + i) * 4 + part] = (anyib || anyic) ? 1 : 0;
    }
}

// ---------------- fused cost + selection: column-per-thread, u64 keys ----------------
// Output interface: rec[col][part] = 64B record {5x u64 key, 5x f32 iou, pad}
__global__ __launch_bounds__(256) void k_main(
    const float* __restrict__ cclsT, const int* __restrict__ labels,
    const float* __restrict__ prmT,
    const float* __restrict__ pboxes, const float* __restrict__ pposes,
    const float* __restrict__ img, const unsigned int* __restrict__ fgw,
    float* __restrict__ costT,
    u64* __restrict__ rec) {
#pragma clang fp contract(off)
    const int j = threadIdx.x;
    const int b = blockIdx.x >> 7;
    const int part = blockIdx.x & 127;
    const int i0 = part * RPP;

    __shared__ float4 Rsh[RPP][5];
    if (threadIdx.x < RPP) {
        const int i = i0 + threadIdx.x;
        const float im0 = img[b * 4 + 0], im1 = img[b * 4 + 1];
        const float im2 = img[b * 4 + 2], im3 = img[b * 4 + 3];
        const float4 bx = *reinterpret_cast<const float4*>(pboxes + ((size_t)(b * QN + i)) * 4);
        const float b0 = bx.x, b1 = bx.y, b2 = bx.z, b3 = bx.w;
        const float2* pp2 = reinterpret_cast<const float2*>(pposes + ((size_t)(b * QN + i)) * 6);
        const float2 q0 = pp2[0], q1 = pp2[1], q2 = pp2[2];
        const float fgadd = fgw[(size_t)b * QN + i] ? 0.0f : 10000.0f;
        const float bn0 = b0 / im0, bn1 = b1 / im1, bn2 = b2 / im2, bn3 = b3 / im3;
        const float a1 = (b2 - b0) * (b3 - b1);
        const float ax = (b0 + b2) * 0.5f, ay = (b1 + b3) * 0.5f;
        Rsh[threadIdx.x][0] = make_float4(b0, b1, b2, b3);
        Rsh[threadIdx.x][1] = make_float4(bn0, bn1, bn2, bn3);
        Rsh[threadIdx.x][2] = make_float4(ax, ay, a1, fgadd);
        Rsh[threadIdx.x][3] = make_float4(q0.x, q0.y, q1.x, q1.y);
        Rsh[threadIdx.x][4] = make_float4(q2.x, q2.y, 0.0f, 0.0f);
    }

    const float* P = prmT + (size_t)b * NPRM * GN;
    const float g0 = P[0 * GN + j], g1 = P[1 * GN + j], g2 = P[2 * GN + j], g3 = P[3 * GN + j];
    const float gn0 = P[4 * GN + j], gn1 = P[5 * GN + j], gn2 = P[6 * GN + j], gn3 = P[7 * GN + j];
    const float t0 = P[8 * GN + j], t1 = P[9 * GN + j], t2 = P[10 * GN + j];
    const float r0 = P[11 * GN + j], r1 = P[12 * GN + j], r2 = P[13 * GN + j];
    const float ga = P[14 * GN + j];
    const float X0 = P[15 * GN + j], Y0 = P[16 * GN + j], X1 = P[17 * GN + j], Y1 = P[18 * GN + j];
    const float LOX = P[19 * GN + j], HIX = P[20 * GN + j], LOY = P[21 * GN + j], HIY = P[22 * GN + j];
    const int lab = labels[b * GN + j];

    const float* CB = cclsT + ((size_t)(b * QN) + i0) * CN;     // uniform base + lab
    float* CT = costT + ((size_t)(b * QN) + i0) * GN + j;

    u64 ck[5]; float iv[5];
#pragma unroll
    for (int k = 0; k < 5; k++) { ck[k] = ~0ull; iv[k] = -1.0f; }

    __syncthreads();

    for (int r = 0; r < RPP; r++) {
        const int i = i0 + r;
        const float4 R0 = Rsh[r][0];
        const float4 R1 = Rsh[r][1];
        const float4 R2 = Rsh[r][2];
        const float4 R3 = Rsh[r][3];
        const float4 R4 = Rsh[r][4];
        const float b0 = R0.x, b1 = R0.y, b2 = R0.z, b3 = R0.w;
        const float bn0 = R1.x, bn1 = R1.y, bn2 = R1.z, bn3 = R1.w;
        const float ax = R2.x, ay = R2.y, a1 = R2.z, fgadd = R2.w;
        const float p0 = R3.x, p1 = R3.y, p2 = R3.z, p3 = R3.w;
        const float p4 = R4.x, p5 = R4.y;
        const float cc = CB[r * CN + lab];

        // iou / giou (f32, reference op order)
        float ltx = fmaxf(b0, g0), lty = fmaxf(b1, g1);
        float rbx = fminf(b2, g2), rby = fminf(b3, g3);
        float w = fmaxf(rbx - ltx, 0.0f), h = fmaxf(rby - lty, 0.0f);
        float inter = w * h;
        float uni = (a1 + ga) - inter;
        float iou = inter / uni;
        float eltx = fminf(b0, g0), elty = fminf(b1, g1);
        float erbx = fmaxf(b2, g2), erby = fmaxf(b3, g3);
        float ew = fmaxf(erbx - eltx, 0.0f), eh = fmaxf(erby - elty, 0.0f);
        float earea = ew * eh;
        float giou = iou - (earea - uni) / earea;

        // normalized bbox L1 (sequential f32)
        float cb = fabsf(bn0 - gn0);
        cb = cb + fabsf(bn1 - gn1);
        cb = cb + fabsf(bn2 - gn2);
        cb = cb + fabsf(bn3 - gn3);
        // pose L1
        float ct = fabsf(p0 - t0); ct = ct + fabsf(p1 - t1); ct = ct + fabsf(p2 - t2);
        float cr = fabsf(p3 - r0); cr = cr + fabsf(p4 - r1); cr = cr + fabsf(p5 - r2);
        // both
        bool ib = (ax > X0) && (ax < X1) && (ay > Y0) && (ay < Y1);
        bool ic = (ax > LOX) && (ax < HIX) && (ay > LOY) && (ay < HIY);
        bool nb = !(ib && ic);

        float d = 5.0f * cb;
        d = d + 2.0f * cc;
        d = d + 2.0f * (-giou);
        d = d + (nb ? 100.0f : 0.0f);
        d = d + ct;
        d = d + cr;
        d = d + fgadd;

        CT[(size_t)r * GN] = d;

        // bottom-5 via u64 key cascade (order-isomorphic to (cost,i) lex)
        u64 key = ((u64)fkey(d) << 32) | (unsigned int)i;
        if (key < ck[4]) {
#pragma unroll
            for (int k = 0; k < 5; k++) {
                u64 mn = key < ck[k] ? key : ck[k];
                u64 mx = key < ck[k] ? ck[k] : key;
                ck[k] = mn; key = mx;
            }
        }
        // top-5 iou via max/min network
        if (iou > iv[4]) {
            float fv = iou;
#pragma unroll
            for (int k = 0; k < 5; k++) {
                float mx = fmaxf(fv, iv[k]);
                fv = fminf(fv, iv[k]);
                iv[k] = mx;
            }
        }
    }

    // pack one 64B record and store as 4x16B (full-line write)
    const int col = b * GN + j;
    u64 buf[8];
#pragma unroll
    for (int k = 0; k < 5; k++) buf[k] = ck[k];
    float* bf = (float*)(buf + 5);
#pragma unroll
    for (int k = 0; k < 5; k++) bf[k] = iv[k];
    bf[5] = 0.0f;                                   // pad -> full 64B line
    ulonglong2* dst = (ulonglong2*)(rec + (((size_t)col * NPART) + part) * 8);
    const ulonglong2* src = (const ulonglong2*)buf;
    dst[0] = src[0]; dst[1] = src[1]; dst[2] = src[2]; dst[3] = src[3];
}

// ---------------- merge parts (wave butterfly), dk, rowmask, rowcnt, amin init ----------------
__global__ __launch_bounds__(256) void k_dk(const u64* __restrict__ rec,
                                            float* __restrict__ candcv, int* __restrict__ candci,
                                            int* __restrict__ dkArr, u64* __restrict__ rowmask,
                                            u64* __restrict__ amin, int* __restrict__ rowcnt) {
#pragma clang fp contract(off)
    const int lane = threadIdx.x & 63;
    const int colIdx = blockIdx.x * 4 + (threadIdx.x >> 6);   // 4 waves/block
    const int b = colIdx >> 8, j = colIdx & 255;
    // rec[col][part]: wave reads parts lane and lane+64 -> two contiguous 4KiB spans
    const u64* R0 = rec + (((size_t)colIdx * NPART) + lane) * 8;
    const u64* R1 = R0 + 64 * 8;
    u64 rv[5]; float fr[5];
    const float* F0 = (const float*)(R0 + 5);
#pragma unroll
    for (int k = 0; k < 5; k++) { rv[k] = R0[k]; fr[k] = F0[k]; }
    const float* F1 = (const float*)(R1 + 5);
#pragma unroll
    for (int m = 0; m < 5; m++) {
        u64 key = R1[m];
        if (key < rv[4]) {
#pragma unroll
            for (int k = 0; k < 5; k++) {
                u64 mn = key < rv[k] ? key : rv[k];
                u64 mx = key < rv[k] ? rv[k] : key;
                rv[k] = mn; key = mx;
            }
        }
        float fv = F1[m];
        if (fv > fr[4]) {
#pragma unroll
            for (int k = 0; k < 5; k++) {
                float mx = fmaxf(fv, fr[k]);
                fv = fminf(fv, fr[k]);
                fr[k] = mx;
            }
        }
    }
    for (int off = 1; off < 64; off <<= 1) {
        u64 ov[5]; float of[5];
#pragma unroll
        for (int m = 0; m < 5; m++) {
            ov[m] = __shfl_xor(rv[m], off, 64);
            of[m] = __shfl_xor(fr[m], off, 64);
        }
#pragma unroll
        for (int m = 0; m < 5; m++) {
            u64 key = ov[m];
            if (key < rv[4]) {
#pragma unroll
                for (int k = 0; k < 5; k++) {
                    u64 mn = key < rv[k] ? key : rv[k];
                    u64 mx = key < rv[k] ? rv[k] : key;
                    rv[k] = mn; key = mx;
                }
            }
            float fv = of[m];
            if (fv > fr[4]) {
#pragma unroll
                for (int k = 0; k < 5; k++) {
                    float mx = fmaxf(fv, fr[k]);
                    fv = fminf(fv, fr[k]);
                    fr[k] = mx;
                }
            }
        }
    }

    if (lane == 0) {
        float sum = ((((fr[0] + fr[1]) + fr[2]) + fr[3]) + fr[4]);  // desc order, sequential
        int dk = (int)sum;
        if (dk < 1) dk = 1;
        if (dk > 5) dk = 5;
        dkArr[colIdx] = dk;
        amin[colIdx] = ~0ull;
#pragma unroll
        for (int k = 0; k < 5; k++) {
            candcv[(size_t)colIdx * 5 + k] = funkey((unsigned int)(rv[k] >> 32));
            candci[(size_t)colIdx * 5 + k] = (int)(unsigned int)(rv[k] & 0xFFFFFFFFull);
        }
        for (int k = 0; k < dk; k++) {
            int i = (int)(unsigned int)(rv[k] & 0xFFFFFFFFull);
            atomicOr(&rowmask[((size_t)(b * QN + i)) * 4 + (j >> 6)], 1ull << (j & 63));
            atomicAdd(&rowcnt[b * QN + i], 1);
        }
    }
}

// ---------------- stale detect + colcnt (1 thread/row, reads rowcnt) ----------------
__global__ __launch_bounds__(256) void k_pen(const int* __restrict__ rowcnt,
                                             const u64* __restrict__ rowmask,
                                             int* __restrict__ colcnt,
                                             int* __restrict__ staleCount,
                                             int* __restrict__ staleList) {
    const int b = blockIdx.x >> 4;
    const int i = (blockIdx.x & 15) * 256 + threadIdx.x;
    const int cnt = rowcnt[b * QN + i];
    if (cnt > 1) {
        int idx = atomicAdd(staleCount, 1);
        staleList[idx] = (b << 12) | i;
    } else if (cnt == 1) {
        const u64* rm = rowmask + ((size_t)(b * QN + i)) * 4;
        u64 w0 = rm[0], w1 = rm[1], w2 = rm[2], w3 = rm[3];
        u64 w; int base;
        if (w0) { w = w0; base = 0; }
        else if (w1) { w = w1; base = 64; }
        else if (w2) { w = w2; base = 128; }
        else { w = w3; base = 192; }
        int j = base + (__ffsll((long long)w) - 1);
        atomicAdd(&colcnt[b * GN + j], 1);
    }
}

// ---------------- fused: wave-parallel stalefix (blocks 0..255) | candidate-assign (256..271) ----
// Racy-monotone colcnt semantics as the verified k_fix; fallback columns (all-5 candidates
// matched) are RECORDED to fbL for parallel resolution in k_fb (not scanned serially here).
__global__ __launch_bounds__(256) void k_fix3(const float* __restrict__ costT,
                                              u64* __restrict__ rowmask,
                                              int* __restrict__ colcnt,
                                              const int* __restrict__ staleCount,
                                              const int* __restrict__ staleList,
                                              int* __restrict__ fixBj,
                                              const int* __restrict__ rowcnt,
                                              const float* __restrict__ candcv,
                                              const int* __restrict__ candci,
                                              u64* __restrict__ amin,
                                              int* __restrict__ fbCount,
                                              int* __restrict__ fbL) {
    if (blockIdx.x < 256) {
        // ---- stalefix: one wave per stale entry, 64-lane scan + shuffle lex-reduce ----
        int gtid = blockIdx.x * blockDim.x + threadIdx.x;
        int wid = gtid >> 6;
        int lane = threadIdx.x & 63;
        int nw = (256 * 256) >> 6;
        int n = *staleCount;
        for (int e = wid; e < n; e += nw) {
            int pk = staleList[e];
            int b = pk >> 12, i = pk & 4095;
            const float* cb = costT + ((size_t)(b * QN) + i) * GN;   // contiguous row
            float best = FLT_MAX; int bj = GN;
            for (int k = 0; k < GN; k += 64) {
                int j = k + lane;
                float v = cb[j];
                if (lexLessF(v, j, best, bj)) { best = v; bj = j; }
            }
            for (int off = 32; off > 0; off >>= 1) {
                float ov = __shfl_down(best, off, 64);
                int oj = __shfl_down(bj, off, 64);
                if (lexLessF(ov, oj, best, bj)) { best = ov; bj = oj; }
            }
            if (lane == 0) {
                u64* rm = rowmask + ((size_t)(b * QN + i)) * 4;
                rm[0] = ((bj >> 6) == 0) ? (1ull << (bj & 63)) : 0ull;
                rm[1] = ((bj >> 6) == 1) ? (1ull << (bj & 63)) : 0ull;
                rm[2] = ((bj >> 6) == 2) ? (1ull << (bj & 63)) : 0ull;
                rm[3] = ((bj >> 6) == 3) ? (1ull << (bj & 63)) : 0ull;
                atomicAdd(&colcnt[b * GN + bj], 1);
                fixBj[e] = bj;
            }
        }
        return;
    }

    // ---- candidate-based assign: 16 blocks, 1 thread/column ----
    const int b = blockIdx.x - 256;
    const int j = threadIdx.x;
    const int col = b * GN + j;

    if (colcnt[col] == 0) {   // racy read; monotone => spurious assigns discarded later
        // first unmatched candidate in sorted bottom-5 == argmin over unmatched rows,
        // since any row outside the bottom-5 has key >= all listed keys.
        bool found = false;
        u64 best = ~0ull;
#pragma unroll
        for (int k = 0; k < 5; k++) {
            if (!found) {
                int i = candci[(size_t)col * 5 + k];
                if (rowcnt[b * QN + i] == 0) {
                    best = ((u64)fkey(candcv[(size_t)col * 5 + k]) << 32) | (unsigned int)i;
                    found = true;
                }
            }
        }
        if (found) {
            amin[col] = best;
        } else {
            int e = atomicAdd(fbCount, 1);   // rare: resolve in k_fb with full parallelism
            fbL[e] = col;
        }
    }
}

// ---------------- parallel fallback resolution: 4 blocks per fallback column ----------------
// amin[col] still ~0ull (k_dk init) for fallback cols; atomicMin over u64 keys = exact
// lex-argmin, associative => chunk order immaterial.
__global__ __launch_bounds__(256) void k_fb(const float* __restrict__ costT,
                                            const int* __restrict__ rowcnt,
                                            const int* __restrict__ fbCount,
                                            const int* __restrict__ fbL,
                                            u64* __restrict__ amin) {
    __shared__ u64 red[256];
    const int n4 = *fbCount * 4;
    const int t = threadIdx.x;
    for (int idx = blockIdx.x; idx < n4; idx += 256) {
        const int e = idx >> 2, chunk = idx & 3;
        const int col = fbL[e];
        const int b = col >> 8, j = col & 255;
        const float* C = costT + ((size_t)(b * QN)) * GN + j;
        const int* rc = rowcnt + b * QN;
        u64 best = ~0ull;
        const int r0 = chunk * 1024;
#pragma unroll
        for (int s = 0; s < 4; s++) {
            int r = r0 + s * 256 + t;
            if (rc[r] == 0) {
                float v = C[(size_t)r * GN];
                u64 key = ((u64)fkey(v) << 32) | (unsigned int)r;
                best = key < best ? key : best;
            }
        }
        red[t] = best;
        __syncthreads();
        for (int s2 = 128; s2 > 0; s2 >>= 1) {
            if (t < s2) { u64 o = red[t + s2]; if (o < red[t]) red[t] = o; }
            __syncthreads();
        }
        if (t == 0 && red[0] != ~0ull) atomicMin(&amin[col], red[0]);
        __syncthreads();   // red reused next iteration
    }
}

__global__ void k_assignfix(const u64* __restrict__ amin,
                            const int* __restrict__ colcnt,
                            int* __restrict__ assign, u64* __restrict__ rowmask) {
    const int col = blockIdx.x * 256 + threadIdx.x;
    const int b = col >> 8, j = col & 255;
    if (colcnt[col] != 0) { assign[col] = -1; return; }
    u64 key = amin[col];
    int r = (int)(unsigned int)(key & 0xFFFFFFFFull);
    assign[col] = r;
    atomicOr(&rowmask[((size_t)(b * QN + r)) * 4 + (j >> 6)], 1ull << (j & 63));
}

// ---------------- fused outputs: outrows (blocks 0..255) | outcols (rest) ----------------
__global__ __launch_bounds__(256) void k_out(const float* __restrict__ costT,
                                             const u64* __restrict__ rowmask,
                                             const int* __restrict__ assign,
                                             const float* __restrict__ candcv,
                                             const int* __restrict__ candci,
                                             const int* __restrict__ dkArr,
                                             const int* __restrict__ staleCount,
                                             const int* __restrict__ staleList,
                                             const int* __restrict__ fixBj,
                                             int* __restrict__ out) {
    if (blockIdx.x < 256) {
        // ---- outrows ----
        const int b = blockIdx.x >> 4;
        const int i = (blockIdx.x & 15) * 256 + threadIdx.x;
        const u64* rm = rowmask + ((size_t)(b * QN + i)) * 4;
        u64 w0 = rm[0], w1 = rm[1], w2 = rm[2], w3 = rm[3];
        int sel = (w0 | w1 | w2 | w3) ? 1 : 0;
        int g = 0;
        if (w0) g = __ffsll((long long)w0) - 1;
        else if (w1) g = 64 + __ffsll((long long)w1) - 1;
        else if (w2) g = 128 + __ffsll((long long)w2) - 1;
        else if (w3) g = 192 + __ffsll((long long)w3) - 1;
        out[(size_t)b * QN + i] = sel;
        out[(size_t)BN * QN + (size_t)b * QN + i] = g;
        return;
    }
    // ---- outcols ----
    const int b = blockIdx.x - 256;
    const int j = threadIdx.x;
    const int col = b * GN + j;
    int* o = out + (size_t)2 * BN * QN + col;
    int a = assign[col];
    if (a >= 0) { *o = a; return; }
    const u64 bit = 1ull << (j & 63);
    const int w = j >> 6;
    float best = FLT_MAX; int bi = INT_MAX;
    const int dk = dkArr[col];
    for (int k = 0; k < 5; k++) {
        if (k < dk) {
            int i = candci[(size_t)col * 5 + k];
            if (rowmask[((size_t)(b * QN + i)) * 4 + w] & bit) {
                float pv = candcv[(size_t)col * 5 + k] + 100000.0f;
                if (lexLessF(pv, i, best, bi)) { best = pv; bi = i; }
            }
        }
    }
    const int n = *staleCount;
    for (int e = 0; e < n; e++) {
        int pk = staleList[e];
        int eb = pk >> 12, ei = pk & 4095;
        if (eb == b && fixBj[e] == j) {
            float pv = costT[((size_t)(b * QN) + ei) * GN + j] + 100000.0f;
            if (lexLessF(pv, ei, best, bi)) { best = pv; bi = ei; }
        }
    }
    *o = (bi == INT_MAX) ? 0 : bi;
}

extern "C" void kernel_launch(void* const* d_in, const int* in_sizes, int n_in,
                              void* d_out, int out_size, void* d_ws, size_t ws_size,
                              hipStream_t stream) {
    const float* logits = (const float*)d_in[0];
    const float* pboxes = (const float*)d_in[1];
    const float* pposes = (const float*)d_in[2];
    const int* labels = (const int*)d_in[3];
    const float* gtb = (const float*)d_in[4];
    const float* gtt = (const float*)d_in[5];
    const float* gtr = (const float*)d_in[6];
    const float* img = (const float*)d_in[7];
    const float* imgt = (const float*)d_in[8];
    int* out = (int*)d_out;

    char* p = (char*)d_ws;
    float* costT = (float*)p;            p += (size_t)BN * QN * GN * 4;        // 64 MiB
    float* cclsT = (float*)p;            p += (size_t)BN * QN * CN * 4;        // 20 MiB
    u64* rec = (u64*)p;                  p += (size_t)BN * GN * NPART * 64;    // 32 MiB (64B/record)
    // ---- zero region: rowmask | colcnt | staleCount+fbCount | rowcnt (contiguous) ----
    u64* rowmask = (u64*)p;              size_t rb = (size_t)BN * QN * 4 * 8; p += rb;  // 2 MiB
    int* colcnt = (int*)p;               p += (size_t)BN * GN * 4;             // 16 KiB
    int* staleCount = (int*)p;           int* fbCount = staleCount + 1; p += 64;
    int* rowcnt = (int*)p;               p += (size_t)BN * QN * 4;             // 256 KiB
    // ---- end zero region ----
    int* staleList = (int*)p;            p += (size_t)BN * QN * 4;             // 256 KiB
    int* fixBj = (int*)p;                p += (size_t)BN * QN * 4;             // 256 KiB
    unsigned char* fgp = (unsigned char*)p; p += (size_t)BN * QN * 4;          // 256 KiB
    int* assign = (int*)p;               p += (size_t)BN * GN * 4;             // 16 KiB
    float* prmT = (float*)p;             p += (size_t)BN * NPRM * GN * 4;      // 376 KiB
    float* candcv = (float*)p;           p += (size_t)BN * GN * 5 * 4;         // 80 KiB
    int* candci = (int*)p;               p += (size_t)BN * GN * 5 * 4;         // 80 KiB
    int* dkArr = (int*)p;                p += (size_t)BN * GN * 4;             // 16 KiB
    u64* amin = (u64*)p;                 p += (size_t)BN * GN * 8;             // 32 KiB
    int* fbL = (int*)p;                  p += (size_t)BN * GN * 4;             // 16 KiB

    // zero region size in u64: rowmask(2MiB) + colcnt(16KiB) + 64B + rowcnt(256KiB)
    int zn = (int)((rb + (size_t)BN * GN * 4 + 64 + (size_t)BN * QN * 4) / 8);  // = 296968

    k_pre<<<NZ_BLK + NC_BLK + NF_BLK, 256, 0, stream>>>(logits, gtb, gtt, gtr, imgt, pboxes,
                                                        rowmask, zn, cclsT, prmT, fgp);
    k_main<<<BN * NPART, 256, 0, stream>>>(cclsT, labels, prmT, pboxes, pposes, img,
                                           (const unsigned int*)fgp, costT, rec);
    k_dk<<<BN * GN / 4, 256, 0, stream>>>(rec, candcv, candci, dkArr, rowmask, amin, rowcnt);
    k_pen<<<256, 256, 0, stream>>>(rowcnt, rowmask, colcnt, staleCount, staleList);
    k_fix3<<<256 + BN, 256, 0, stream>>>(costT, rowmask, colcnt, staleCount, staleList,
                                         fixBj, rowcnt, candcv, candci, amin, fbCount, fbL);
    k_fb<<<256, 256, 0, stream>>>(costT, rowcnt, fbCount, fbL, amin);
    k_assignfix<<<BN * GN / 256, 256, 0, stream>>>(amin, colcnt, assign, rowmask);
    k_out<<<256 + BN, 256, 0, stream>>>(costT, rowmask, assign, candcv, candci, dkArr,
                                        staleCount, staleList, fixBj, out);
}

// Round 10
// 226.254 us; speedup vs baseline: 1.6213x; 1.1986x over previous
//
#include <hip/hip_runtime.h>
#include <cfloat>
#include <climits>
#include <math.h>

#define BN 16
#define QN 4096
#define GN 256
#define CN 80
#define NPART 128          // row parts in k_main (32 rows each)
#define RPP (QN / NPART)   // 32
#define NPRM 23            // column params

// k_pre sub-grid sizes
#define NZ_BLK 1161        // zero: ceil(296968/256)
#define NC_BLK 2048        // class: 16 b x 64 iblk x 2 half
#define NF_BLK 1024        // fg: 16 itile x 16 b x 4 part

typedef unsigned long long u64;

__device__ __forceinline__ bool lexLessF(float a, int ia, float b, int ib) {
    return (a < b) || (a == b && ia < ib);
}
// IEEE order-isomorphic u32 key (no NaNs in this data)
__device__ __forceinline__ unsigned int fkey(float f) {
    unsigned int b = __float_as_uint(f);
    return b ^ ((b >> 31) ? 0xFFFFFFFFu : 0x80000000u);
}
__device__ __forceinline__ float funkey(unsigned int k) {
    unsigned int b = k ^ ((k >> 31) ? 0x80000000u : 0xFFFFFFFFu);
    return __uint_as_float(b);
}

// ---------------- mega pre-kernel: zero | class | fg ----------------
__global__ __launch_bounds__(256) void k_pre(const float* __restrict__ logits,
                                             const float* __restrict__ gtb,
                                             const float* __restrict__ gtt,
                                             const float* __restrict__ gtr,
                                             const float* __restrict__ imgt,
                                             const float* __restrict__ pb,
                                             u64* __restrict__ zbase, int zn,
                                             float* __restrict__ cclsT,
                                             float* __restrict__ prmT,
                                             unsigned char* __restrict__ fgp) {
#pragma clang fp contract(off)
    const int blk = blockIdx.x;
    if (blk < NZ_BLK) {
        int i = blk * 256 + threadIdx.x;
        if (i < zn) zbase[i] = 0ull;
        return;
    }
    if (blk < NZ_BLK + NC_BLK) {
        // ---- class: ccls[b][i][c] (10 classes/thread, float2) + prm ----
        const int bid = blk - NZ_BLK;
        const int b = bid >> 7;
        const int rem = bid & 127;
        const int iblk = rem >> 1, h = rem & 1;
        const int lane = threadIdx.x & 63, cg_ = threadIdx.x >> 6;
        const int i = iblk * 64 + lane;
        const int c0 = h * 40 + cg_ * 10;
        const float* lrow = logits + ((size_t)(b * QN + i)) * CN + c0;
        float* orow = cclsT + ((size_t)(b * QN + i)) * CN + c0;
#pragma unroll
        for (int q = 0; q < 5; q++) {
            const float2 xv = *reinterpret_cast<const float2*>(lrow + q * 2);
            float xs[2] = {xv.x, xv.y};
            float os[2];
#pragma unroll
            for (int u = 0; u < 2; u++) {
                float x = xs[u];
                float e = (float)exp(-(double)x);
                float pr = 1.0f / (1.0f + e);
                float om = 1.0f - pr;
                float lneg = (float)log((double)(om + 1e-8f));
                float lpos = (float)log((double)(pr + 1e-8f));
                float neg = (0.75f * (pr * pr)) * (-lneg);
                float pos = (0.25f * (om * om)) * (-lpos);
                os[u] = pos - neg;
            }
            *reinterpret_cast<float2*>(orow + q * 2) = make_float2(os[0], os[1]);
        }
        if (rem == 0) {
            const int j = threadIdx.x;
            const float* g = gtb + ((size_t)(b * GN + j)) * 4;
            const float g0 = g[0], g1 = g[1], g2 = g[2], g3 = g[3];
            const float* it = imgt + ((size_t)(b * GN + j)) * 4;
            float* P = prmT + (size_t)b * NPRM * GN;
            P[0 * GN + j] = g0; P[1 * GN + j] = g1; P[2 * GN + j] = g2; P[3 * GN + j] = g3;
            P[4 * GN + j] = g0 / it[0]; P[5 * GN + j] = g1 / it[1];
            P[6 * GN + j] = g2 / it[2]; P[7 * GN + j] = g3 / it[3];
            P[8 * GN + j] = gtt[(b * GN + j) * 3 + 0]; P[9 * GN + j] = gtt[(b * GN + j) * 3 + 1];
            P[10 * GN + j] = gtt[(b * GN + j) * 3 + 2];
            P[11 * GN + j] = gtr[(b * GN + j) * 3 + 0]; P[12 * GN + j] = gtr[(b * GN + j) * 3 + 1];
            P[13 * GN + j] = gtr[(b * GN + j) * 3 + 2];
            P[14 * GN + j] = (g2 - g0) * (g3 - g1);   // ga
            float gcx = (g0 + g2) * 0.5f, gcy = (g1 + g3) * 0.5f;
            float gw = g2 - g0, gh = g3 - g1;
            float X0 = gcx - gw * 0.5f, Y0 = gcy - gh * 0.5f;
            float X1 = gcx + gw * 0.5f, Y1 = gcy + gh * 0.5f;
            float Wd = X1 - X0, Hd = Y1 - Y0;
            P[15 * GN + j] = X0; P[16 * GN + j] = Y0; P[17 * GN + j] = X1; P[18 * GN + j] = Y1;
            P[19 * GN + j] = gcx - 2.5f * Wd; P[20 * GN + j] = gcx + 2.5f * Wd;
            P[21 * GN + j] = gcy - 2.5f * Hd; P[22 * GN + j] = gcy + 2.5f * Hd;
        }
        return;
    }
    // ---- fg: 4-way j-split, float4 LDS ----
    {
        const int bid = blk - NZ_BLK - NC_BLK;       // itile(16) x b(16) x part(4)
        const int itile = bid >> 6;
        const int b = (bid >> 2) & 15;
        const int part = bid & 3;
        const int i = itile * 256 + threadIdx.x;
        __shared__ float4 sA[64], sB[64];
        if (threadIdx.x < 64) {
            const int j = part * 64 + threadIdx.x;
            const float* g = gtb + ((size_t)(b * GN + j)) * 4;
            float g0 = g[0], g1 = g[1], g2 = g[2], g3 = g[3];
            float gcx = (g0 + g2) * 0.5f, gcy = (g1 + g3) * 0.5f;
            float gw = g2 - g0, gh = g3 - g1;
            float x0 = gcx - gw * 0.5f, y0 = gcy - gh * 0.5f;
            float x1 = gcx + gw * 0.5f, y1 = gcy + gh * 0.5f;
            float w = x1 - x0, h2 = y1 - y0;
            sA[threadIdx.x] = make_float4(x0, y0, x1, y1);
            sB[threadIdx.x] = make_float4(gcx - 2.5f * w, gcx + 2.5f * w,
                                          gcy - 2.5f * h2, gcy + 2.5f * h2);
        }
        __syncthreads();
        const float4 bb = *reinterpret_cast<const float4*>(pb + ((size_t)(b * QN + i)) * 4);
        float ax = (bb.x + bb.z) * 0.5f, ay = (bb.y + bb.w) * 0.5f;
        bool anyib = false, anyic = false;
#pragma unroll 8
        for (int j = 0; j < 64; j++) {
            const float4 A = sA[j], B = sB[j];
            bool ib = (ax > A.x) && (ax < A.z) && (ay > A.y) && (ay < A.w);
            bool ic = (ax > B.x) && (ax < B.y) && (ay > B.z) && (ay < B.w);
            anyib |= ib; anyic |= ic;
        }
        fgp[((size_t)b * QN + i) * 4 + part] = (anyib || anyic) ? 1 : 0;
    }
}

// ---------------- fused cost + selection: column-per-thread, u64 keys ----------------
// Output interface: rec[col][part] = 64B record {5x u64 key, 5x f32 iou, pad}
__global__ __launch_bounds__(256) void k_main(
    const float* __restrict__ cclsT, const int* __restrict__ labels,
    const float* __restrict__ prmT,
    const float* __restrict__ pboxes, const float* __restrict__ pposes,
    const float* __restrict__ img, const unsigned int* __restrict__ fgw,
    float* __restrict__ costT,
    u64* __restrict__ rec) {
#pragma clang fp contract(off)
    const int j = threadIdx.x;
    const int b = blockIdx.x >> 7;
    const int part = blockIdx.x & 127;
    const int i0 = part * RPP;

    __shared__ float4 Rsh[RPP][5];
    if (threadIdx.x < RPP) {
        const int i = i0 + threadIdx.x;
        const float im0 = img[b * 4 + 0], im1 = img[b * 4 + 1];
        const float im2 = img[b * 4 + 2], im3 = img[b * 4 + 3];
        const float4 bx = *reinterpret_cast<const float4*>(pboxes + ((size_t)(b * QN + i)) * 4);
        const float b0 = bx.x, b1 = bx.y, b2 = bx.z, b3 = bx.w;
        const float2* pp2 = reinterpret_cast<const float2*>(pposes + ((size_t)(b * QN + i)) * 6);
        const float2 q0 = pp2[0], q1 = pp2[1], q2 = pp2[2];
        const float fgadd = fgw[(size_t)b * QN + i] ? 0.0f : 10000.0f;
        const float bn0 = b0 / im0, bn1 = b1 / im1, bn2 = b2 / im2, bn3 = b3 / im3;
        const float a1 = (b2 - b0) * (b3 - b1);
        const float ax = (b0 + b2) * 0.5f, ay = (b1 + b3) * 0.5f;
        Rsh[threadIdx.x][0] = make_float4(b0, b1, b2, b3);
        Rsh[threadIdx.x][1] = make_float4(bn0, bn1, bn2, bn3);
        Rsh[threadIdx.x][2] = make_float4(ax, ay, a1, fgadd);
        Rsh[threadIdx.x][3] = make_float4(q0.x, q0.y, q1.x, q1.y);
        Rsh[threadIdx.x][4] = make_float4(q2.x, q2.y, 0.0f, 0.0f);
    }

    const float* P = prmT + (size_t)b * NPRM * GN;
    const float g0 = P[0 * GN + j], g1 = P[1 * GN + j], g2 = P[2 * GN + j], g3 = P[3 * GN + j];
    const float gn0 = P[4 * GN + j], gn1 = P[5 * GN + j], gn2 = P[6 * GN + j], gn3 = P[7 * GN + j];
    const float t0 = P[8 * GN + j], t1 = P[9 * GN + j], t2 = P[10 * GN + j];
    const float r0 = P[11 * GN + j], r1 = P[12 * GN + j], r2 = P[13 * GN + j];
    const float ga = P[14 * GN + j];
    const float X0 = P[15 * GN + j], Y0 = P[16 * GN + j], X1 = P[17 * GN + j], Y1 = P[18 * GN + j];
    const float LOX = P[19 * GN + j], HIX = P[20 * GN + j], LOY = P[21 * GN + j], HIY = P[22 * GN + j];
    const int lab = labels[b * GN + j];

    const float* CB = cclsT + ((size_t)(b * QN) + i0) * CN;     // uniform base + lab
    float* CT = costT + ((size_t)(b * QN) + i0) * GN + j;

    u64 ck[5]; float iv[5];
#pragma unroll
    for (int k = 0; k < 5; k++) { ck[k] = ~0ull; iv[k] = -1.0f; }

    __syncthreads();

    for (int r = 0; r < RPP; r++) {
        const int i = i0 + r;
        const float4 R0 = Rsh[r][0];
        const float4 R1 = Rsh[r][1];
        const float4 R2 = Rsh[r][2];
        const float4 R3 = Rsh[r][3];
        const float4 R4 = Rsh[r][4];
        const float b0 = R0.x, b1 = R0.y, b2 = R0.z, b3 = R0.w;
        const float bn0 = R1.x, bn1 = R1.y, bn2 = R1.z, bn3 = R1.w;
        const float ax = R2.x, ay = R2.y, a1 = R2.z, fgadd = R2.w;
        const float p0 = R3.x, p1 = R3.y, p2 = R3.z, p3 = R3.w;
        const float p4 = R4.x, p5 = R4.y;
        const float cc = CB[r * CN + lab];

        // iou / giou (f32, reference op order)
        float ltx = fmaxf(b0, g0), lty = fmaxf(b1, g1);
        float rbx = fminf(b2, g2), rby = fminf(b3, g3);
        float w = fmaxf(rbx - ltx, 0.0f), h = fmaxf(rby - lty, 0.0f);
        float inter = w * h;
        float uni = (a1 + ga) - inter;
        float iou = inter / uni;
        float eltx = fminf(b0, g0), elty = fminf(b1, g1);
        float erbx = fmaxf(b2, g2), erby = fmaxf(b3, g3);
        float ew = fmaxf(erbx - eltx, 0.0f), eh = fmaxf(erby - elty, 0.0f);
        float earea = ew * eh;
        float giou = iou - (earea - uni) / earea;

        // normalized bbox L1 (sequential f32)
        float cb = fabsf(bn0 - gn0);
        cb = cb + fabsf(bn1 - gn1);
        cb = cb + fabsf(bn2 - gn2);
        cb = cb + fabsf(bn3 - gn3);
        // pose L1
        float ct = fabsf(p0 - t0); ct = ct + fabsf(p1 - t1); ct = ct + fabsf(p2 - t2);
        float cr = fabsf(p3 - r0); cr = cr + fabsf(p4 - r1); cr = cr + fabsf(p5 - r2);
        // both
        bool ib = (ax > X0) && (ax < X1) && (ay > Y0) && (ay < Y1);
        bool ic = (ax > LOX) && (ax < HIX) && (ay > LOY) && (ay < HIY);
        bool nb = !(ib && ic);

        float d = 5.0f * cb;
        d = d + 2.0f * cc;
        d = d + 2.0f * (-giou);
        d = d + (nb ? 100.0f : 0.0f);
        d = d + ct;
        d = d + cr;
        d = d + fgadd;

        CT[(size_t)r * GN] = d;

        // bottom-5 via u64 key cascade (order-isomorphic to (cost,i) lex)
        u64 key = ((u64)fkey(d) << 32) | (unsigned int)i;
        if (key < ck[4]) {
#pragma unroll
            for (int k = 0; k < 5; k++) {
                u64 mn = key < ck[k] ? key : ck[k];
                u64 mx = key < ck[k] ? ck[k] : key;
                ck[k] = mn; key = mx;
            }
        }
        // top-5 iou via max/min network
        if (iou > iv[4]) {
            float fv = iou;
#pragma unroll
            for (int k = 0; k < 5; k++) {
                float mx = fmaxf(fv, iv[k]);
                fv = fminf(fv, iv[k]);
                iv[k] = mx;
            }
        }
    }

    // pack one 64B record and store as 4x16B (full-line write)
    const int col = b * GN + j;
    u64 buf[8];
#pragma unroll
    for (int k = 0; k < 5; k++) buf[k] = ck[k];
    float* bf = (float*)(buf + 5);
#pragma unroll
    for (int k = 0; k < 5; k++) bf[k] = iv[k];
    bf[5] = 0.0f;                                   // pad -> full 64B line
    ulonglong2* dst = (ulonglong2*)(rec + (((size_t)col * NPART) + part) * 8);
    const ulonglong2* src = (const ulonglong2*)buf;
    dst[0] = src[0]; dst[1] = src[1]; dst[2] = src[2]; dst[3] = src[3];
}

// ---------------- merge parts (wave butterfly), dk, rowmask, rowcnt, amin/staleAmin init ----
__global__ __launch_bounds__(256) void k_dk(const u64* __restrict__ rec,
                                            float* __restrict__ candcv, int* __restrict__ candci,
                                            int* __restrict__ dkArr, u64* __restrict__ rowmask,
                                            u64* __restrict__ amin, int* __restrict__ rowcnt,
                                            u64* __restrict__ staleAmin) {
#pragma clang fp contract(off)
    const int lane = threadIdx.x & 63;
    const int colIdx = blockIdx.x * 4 + (threadIdx.x >> 6);   // 4 waves/block
    const int b = colIdx >> 8, j = colIdx & 255;
    // rec[col][part]: wave reads parts lane and lane+64 -> two contiguous 4KiB spans
    const u64* R0 = rec + (((size_t)colIdx * NPART) + lane) * 8;
    const u64* R1 = R0 + 64 * 8;
    u64 rv[5]; float fr[5];
    const float* F0 = (const float*)(R0 + 5);
#pragma unroll
    for (int k = 0; k < 5; k++) { rv[k] = R0[k]; fr[k] = F0[k]; }
    const float* F1 = (const float*)(R1 + 5);
#pragma unroll
    for (int m = 0; m < 5; m++) {
        u64 key = R1[m];
        if (key < rv[4]) {
#pragma unroll
            for (int k = 0; k < 5; k++) {
                u64 mn = key < rv[k] ? key : rv[k];
                u64 mx = key < rv[k] ? rv[k] : key;
                rv[k] = mn; key = mx;
            }
        }
        float fv = F1[m];
        if (fv > fr[4]) {
#pragma unroll
            for (int k = 0; k < 5; k++) {
                float mx = fmaxf(fv, fr[k]);
                fv = fminf(fv, fr[k]);
                fr[k] = mx;
            }
        }
    }
    for (int off = 1; off < 64; off <<= 1) {
        u64 ov[5]; float of[5];
#pragma unroll
        for (int m = 0; m < 5; m++) {
            ov[m] = __shfl_xor(rv[m], off, 64);
            of[m] = __shfl_xor(fr[m], off, 64);
        }
#pragma unroll
        for (int m = 0; m < 5; m++) {
            u64 key = ov[m];
            if (key < rv[4]) {
#pragma unroll
                for (int k = 0; k < 5; k++) {
                    u64 mn = key < rv[k] ? key : rv[k];
                    u64 mx = key < rv[k] ? rv[k] : key;
                    rv[k] = mn; key = mx;
                }
            }
            float fv = of[m];
            if (fv > fr[4]) {
#pragma unroll
                for (int k = 0; k < 5; k++) {
                    float mx = fmaxf(fv, fr[k]);
                    fv = fminf(fv, fr[k]);
                    fr[k] = mx;
                }
            }
        }
    }

    if (lane == 0) {
        float sum = ((((fr[0] + fr[1]) + fr[2]) + fr[3]) + fr[4]);  // desc order, sequential
        int dk = (int)sum;
        if (dk < 1) dk = 1;
        if (dk > 5) dk = 5;
        dkArr[colIdx] = dk;
        amin[colIdx] = ~0ull;
        staleAmin[colIdx] = ~0ull;
#pragma unroll
        for (int k = 0; k < 5; k++) {
            candcv[(size_t)colIdx * 5 + k] = funkey((unsigned int)(rv[k] >> 32));
            candci[(size_t)colIdx * 5 + k] = (int)(unsigned int)(rv[k] & 0xFFFFFFFFull);
        }
        for (int k = 0; k < dk; k++) {
            int i = (int)(unsigned int)(rv[k] & 0xFFFFFFFFull);
            atomicOr(&rowmask[((size_t)(b * QN + i)) * 4 + (j >> 6)], 1ull << (j & 63));
            atomicAdd(&rowcnt[b * QN + i], 1);
        }
    }
}

// ---------------- fused: detect+wave-fix+colcnt (blocks 0..255) | candidate-assign (256..271) ----
// Row side: ballot-based stale detect + wave-cooperative fix; resolved stale winners recorded
// per-column via atomicMin on staleAmin (order-isomorphic key) -> k_out reads one word instead
// of looping a stale list. Assign side reads colcnt racy-monotone (verified semantics: final
// arbiter is k_fba's post-completion colcnt read; spurious amin/fbL entries are discarded).
__global__ __launch_bounds__(256) void k_fix5(const float* __restrict__ costT,
                                              u64* __restrict__ rowmask,
                                              int* __restrict__ colcnt,
                                              const int* __restrict__ rowcnt,
                                              const float* __restrict__ candcv,
                                              const int* __restrict__ candci,
                                              u64* __restrict__ amin,
                                              u64* __restrict__ staleAmin,
                                              int* __restrict__ fbCount,
                                              int* __restrict__ fbL) {
    if (blockIdx.x < 256) {
        // ---- row side: per-thread detect, wave-cooperative fix ----
        const int b = blockIdx.x >> 4;
        const int i = (blockIdx.x & 15) * 256 + threadIdx.x;
        const int lane = threadIdx.x & 63;
        const int cnt = rowcnt[b * QN + i];
        if (cnt == 1) {
            const u64* rm = rowmask + ((size_t)(b * QN + i)) * 4;
            u64 w0 = rm[0], w1 = rm[1], w2 = rm[2], w3 = rm[3];
            u64 w; int base;
            if (w0) { w = w0; base = 0; }
            else if (w1) { w = w1; base = 64; }
            else if (w2) { w = w2; base = 128; }
            else { w = w3; base = 192; }
            int jj = base + (__ffsll((long long)w) - 1);
            atomicAdd(&colcnt[b * GN + jj], 1);
        }
        // wave-cooperative fix of flagged (stale) rows, one at a time
        u64 bal = __ballot(cnt > 1);
        while (bal) {
            const int L = __ffsll((long long)bal) - 1;
            bal &= bal - 1;
            const int iL = (i & ~63) | L;
            const float* cb = costT + ((size_t)(b * QN) + iL) * GN;   // contiguous row
            float best = FLT_MAX; int bj = GN;
            for (int k = 0; k < GN; k += 64) {
                int jj = k + lane;
                float v = cb[jj];
                if (lexLessF(v, jj, best, bj)) { best = v; bj = jj; }
            }
            for (int off = 32; off > 0; off >>= 1) {
                float ov = __shfl_down(best, off, 64);
                int oj = __shfl_down(bj, off, 64);
                if (lexLessF(ov, oj, best, bj)) { best = ov; bj = oj; }
            }
            if (lane == 0) {
                u64* rm = rowmask + ((size_t)(b * QN + iL)) * 4;
                rm[0] = ((bj >> 6) == 0) ? (1ull << (bj & 63)) : 0ull;
                rm[1] = ((bj >> 6) == 1) ? (1ull << (bj & 63)) : 0ull;
                rm[2] = ((bj >> 6) == 2) ? (1ull << (bj & 63)) : 0ull;
                rm[3] = ((bj >> 6) == 3) ? (1ull << (bj & 63)) : 0ull;
                atomicAdd(&colcnt[b * GN + bj], 1);
                // record stale winner for k_out: pv = best + 100000, tie-break by row index
                float pv = best + 100000.0f;
                u64 key = ((u64)fkey(pv) << 32) | (unsigned int)iL;
                atomicMin(&staleAmin[b * GN + bj], key);
            }
        }
        return;
    }

    // ---- candidate-based assign: 16 blocks, 1 thread/column ----
    const int b = blockIdx.x - 256;
    const int j = threadIdx.x;
    const int col = b * GN + j;

    if (colcnt[col] == 0) {   // racy read; monotone => spurious work discarded later
        // first unmatched candidate in sorted bottom-5 == argmin over unmatched rows,
        // since any row outside the bottom-5 has key >= all listed keys.
        bool found = false;
        u64 best = ~0ull;
#pragma unroll
        for (int k = 0; k < 5; k++) {
            if (!found) {
                int i = candci[(size_t)col * 5 + k];
                if (rowcnt[b * QN + i] == 0) {
                    best = ((u64)fkey(candcv[(size_t)col * 5 + k]) << 32) | (unsigned int)i;
                    found = true;
                }
            }
        }
        if (found) {
            amin[col] = best;
        } else {
            int e = atomicAdd(fbCount, 1);   // rare: resolve in k_fba with full parallelism
            fbL[e] = col;
        }
    }
}

// ---------------- fused: assign-finalize (blocks 0..15) | fallback scans (blocks 16..271) ----
// Blocks 0..15: final colcnt is the arbiter; unmatched cols with amin set get assigned;
// unmatched cols with amin==~0ull (true fallbacks) are SKIPPED (fallback blocks own them).
// Fallback blocks: one block per fbL entry (grid-stride), 256-thread strided column scan over
// unmatched rows + LDS lex-min reduce, then direct assign + rowmask OR.
__global__ __launch_bounds__(256) void k_fba(const float* __restrict__ costT,
                                             const int* __restrict__ rowcnt,
                                             const int* __restrict__ colcnt,
                                             const u64* __restrict__ amin,
                                             const int* __restrict__ fbCount,
                                             const int* __restrict__ fbL,
                                             int* __restrict__ assign,
                                             u64* __restrict__ rowmask) {
    if (blockIdx.x < BN) {
        const int b = blockIdx.x;
        const int j = threadIdx.x;
        const int col = b * GN + j;
        if (colcnt[col] != 0) { assign[col] = -1; return; }
        u64 key = amin[col];
        if (key == ~0ull) return;            // fallback column: handled by scan blocks
        int r = (int)(unsigned int)(key & 0xFFFFFFFFull);
        assign[col] = r;
        atomicOr(&rowmask[((size_t)(b * QN + r)) * 4 + (j >> 6)], 1ull << (j & 63));
        return;
    }
    // ---- fallback scans ----
    __shared__ u64 red[256];
    const int n = *fbCount;
    const int t = threadIdx.x;
    for (int e = blockIdx.x - BN; e < n; e += 256) {
        const int col = fbL[e];
        const int b = col >> 8, j = col & 255;
        if (colcnt[col] != 0) continue;      // spuriously recorded; assign=-1 already written
        const float* C = costT + ((size_t)(b * QN)) * GN + j;
        const int* rc = rowcnt + b * QN;
        u64 best = ~0ull;
#pragma unroll
        for (int s = 0; s < 16; s++) {
            int r = s * 256 + t;
            if (rc[r] == 0) {
                float v = C[(size_t)r * GN];
                u64 key = ((u64)fkey(v) << 32) | (unsigned int)r;
                best = key < best ? key : best;
            }
        }
        red[t] = best;
        __syncthreads();
        for (int s2 = 128; s2 > 0; s2 >>= 1) {
            if (t < s2) { u64 o = red[t + s2]; if (o < red[t]) red[t] = o; }
            __syncthreads();
        }
        if (t == 0) {
            int r = (int)(unsigned int)(red[0] & 0xFFFFFFFFull);
            assign[col] = r;
            atomicOr(&rowmask[((size_t)(b * QN + r)) * 4 + (j >> 6)], 1ull << (j & 63));
        }
        __syncthreads();   // red reused next iteration
    }
}

// ---------------- fused outputs: outrows (blocks 0..255) | outcols (256..271) ----------------
__global__ __launch_bounds__(256) void k_out(const u64* __restrict__ rowmask,
                                             const int* __restrict__ assign,
                                             const float* __restrict__ candcv,
                                             const int* __restrict__ candci,
                                             const int* __restrict__ dkArr,
                                             const u64* __restrict__ staleAmin,
                                             int* __restrict__ out) {
    if (blockIdx.x < 256) {
        // ---- outrows ----
        const int b = blockIdx.x >> 4;
        const int i = (blockIdx.x & 15) * 256 + threadIdx.x;
        const u64* rm = rowmask + ((size_t)(b * QN + i)) * 4;
        u64 w0 = rm[0], w1 = rm[1], w2 = rm[2], w3 = rm[3];
        int sel = (w0 | w1 | w2 | w3) ? 1 : 0;
        int g = 0;
        if (w0) g = __ffsll((long long)w0) - 1;
        else if (w1) g = 64 + __ffsll((long long)w1) - 1;
        else if (w2) g = 128 + __ffsll((long long)w2) - 1;
        else if (w3) g = 192 + __ffsll((long long)w3) - 1;
        out[(size_t)b * QN + i] = sel;
        out[(size_t)BN * QN + (size_t)b * QN + i] = g;
        return;
    }
    // ---- outcols ----
    const int b = blockIdx.x - 256;
    const int j = threadIdx.x;
    const int col = b * GN + j;
    int* o = out + (size_t)2 * BN * QN + col;
    int a = assign[col];
    if (a >= 0) { *o = a; return; }
    const u64 bit = 1ull << (j & 63);
    const int w = j >> 6;
    float best = FLT_MAX; int bi = INT_MAX;
    const int dk = dkArr[col];
    for (int k = 0; k < 5; k++) {
        if (k < dk) {
            int i = candci[(size_t)col * 5 + k];
            if (rowmask[((size_t)(b * QN + i)) * 4 + w] & bit) {
                float pv = candcv[(size_t)col * 5 + k] + 100000.0f;
                if (lexLessF(pv, i, best, bi)) { best = pv; bi = i; }
            }
        }
    }
    // stale winner for this column (lex-min over all stale rows fixed to j), one read
    const u64 sk = staleAmin[col];
    if (sk != ~0ull) {
        float pv = funkey((unsigned int)(sk >> 32));
        int ei = (int)(unsigned int)(sk & 0xFFFFFFFFull);
        if (lexLessF(pv, ei, best, bi)) { best = pv; bi = ei; }
    }
    *o = (bi == INT_MAX) ? 0 : bi;
}

extern "C" void kernel_launch(void* const* d_in, const int* in_sizes, int n_in,
                              void* d_out, int out_size, void* d_ws, size_t ws_size,
                              hipStream_t stream) {
    const float* logits = (const float*)d_in[0];
    const float* pboxes = (const float*)d_in[1];
    const float* pposes = (const float*)d_in[2];
    const int* labels = (const int*)d_in[3];
    const float* gtb = (const float*)d_in[4];
    const float* gtt = (const float*)d_in[5];
    const float* gtr = (const float*)d_in[6];
    const float* img = (const float*)d_in[7];
    const float* imgt = (const float*)d_in[8];
    int* out = (int*)d_out;

    char* p = (char*)d_ws;
    float* costT = (float*)p;            p += (size_t)BN * QN * GN * 4;        // 64 MiB
    float* cclsT = (float*)p;            p += (size_t)BN * QN * CN * 4;        // 20 MiB
    u64* rec = (u64*)p;                  p += (size_t)BN * GN * NPART * 64;    // 32 MiB (64B/record)
    // ---- zero region: rowmask | colcnt | fbCount | rowcnt (contiguous) ----
    u64* rowmask = (u64*)p;              size_t rb = (size_t)BN * QN * 4 * 8; p += rb;  // 2 MiB
    int* colcnt = (int*)p;               p += (size_t)BN * GN * 4;             // 16 KiB
    int* fbCount = (int*)p;              p += 64;
    int* rowcnt = (int*)p;               p += (size_t)BN * QN * 4;             // 256 KiB
    // ---- end zero region ----
    unsigned char* fgp = (unsigned char*)p; p += (size_t)BN * QN * 4;          // 256 KiB
    int* assign = (int*)p;               p += (size_t)BN * GN * 4;             // 16 KiB
    float* prmT = (float*)p;             p += (size_t)BN * NPRM * GN * 4;      // 376 KiB
    float* candcv = (float*)p;           p += (size_t)BN * GN * 5 * 4;         // 80 KiB
    int* candci = (int*)p;               p += (size_t)BN * GN * 5 * 4;         // 80 KiB
    int* dkArr = (int*)p;                p += (size_t)BN * GN * 4;             // 16 KiB
    u64* amin = (u64*)p;                 p += (size_t)BN * GN * 8;             // 32 KiB
    u64* staleAmin = (u64*)p;            p += (size_t)BN * GN * 8;             // 32 KiB (init in k_dk)
    int* fbL = (int*)p;                  p += (size_t)BN * GN * 4;             // 16 KiB

    // zero region size in u64: rowmask(2MiB) + colcnt(16KiB) + 64B + rowcnt(256KiB)
    int zn = (int)((rb + (size_t)BN * GN * 4 + 64 + (size_t)BN * QN * 4) / 8);  // = 296968

    k_pre<<<NZ_BLK + NC_BLK + NF_BLK, 256, 0, stream>>>(logits, gtb, gtt, gtr, imgt, pboxes,
                                                        rowmask, zn, cclsT, prmT, fgp);
    k_main<<<BN * NPART, 256, 0, stream>>>(cclsT, labels, prmT, pboxes, pposes, img,
                                           (const unsigned int*)fgp, costT, rec);
    k_dk<<<BN * GN / 4, 256, 0, stream>>>(rec, candcv, candci, dkArr, rowmask, amin, rowcnt,
                                          staleAmin);
    k_fix5<<<256 + BN, 256, 0, stream>>>(costT, rowmask, colcnt, rowcnt, candcv, candci,
                                         amin, staleAmin, fbCount, fbL);
    k_fba<<<BN + 256, 256, 0, stream>>>(costT, rowcnt, colcnt, amin, fbCount, fbL,
                                        assign, rowmask);
    k_out<<<256 + BN, 256, 0, stream>>>(rowmask, assign, candcv, candci, dkArr, staleAmin, out);
}

// Round 11
// 218.515 us; speedup vs baseline: 1.6788x; 1.0354x over previous
//
#include <hip/hip_runtime.h>
#include <cfloat>
#include <climits>
#include <math.h>

#define BN 16
#define QN 4096
#define GN 256
#define CN 80
#define NPART 128          // row parts in k_main (32 rows each)
#define RPP (QN / NPART)   // 32
#define NZ_BLK 1161        // zero slice blocks: ceil(296968/256)

typedef unsigned long long u64;

__device__ __forceinline__ bool lexLessF(float a, int ia, float b, int ib) {
    return (a < b) || (a == b && ia < ib);
}
// IEEE order-isomorphic u32 key (no NaNs in this data)
__device__ __forceinline__ unsigned int fkey(float f) {
    unsigned int b = __float_as_uint(f);
    return b ^ ((b >> 31) ? 0xFFFFFFFFu : 0x80000000u);
}
__device__ __forceinline__ float funkey(unsigned int k) {
    unsigned int b = k ^ ((k >> 31) ? 0x80000000u : 0xFFFFFFFFu);
    return __uint_as_float(b);
}

// ---------------- fully-fused front-end: zero | prm | class | fg | cost | selection ----------
// Each block owns rows i0..i0+31 of batch b exclusively, so all former k_pre work partitions
// exactly along this grid. All numerics are the identical expressions (contract off) ->
// bit-identical costs. Output: costT + rec[col][part] 64B records.
__global__ __launch_bounds__(256) void k_main(
    const float* __restrict__ logits, const int* __restrict__ labels,
    const float* __restrict__ gtb, const float* __restrict__ gtt,
    const float* __restrict__ gtr, const float* __restrict__ imgt,
    const float* __restrict__ pboxes, const float* __restrict__ pposes,
    const float* __restrict__ img,
    float* __restrict__ costT, u64* __restrict__ rec,
    u64* __restrict__ zbase, int zn) {
#pragma clang fp contract(off)
    const int j = threadIdx.x;
    const int b = blockIdx.x >> 7;
    const int part = blockIdx.x & 127;
    const int i0 = part * RPP;

    __shared__ float Lc[RPP * CN];       // 32x80 focal class costs (10 KB)
    __shared__ float Lb[8 * GN];         // X0,Y0,X1,Y1,LOX,HIX,LOY,HIY per column (8 KB)
    __shared__ unsigned int Lfg[RPP * 8];
    __shared__ float fgf[RPP];
    __shared__ float4 Rsh[RPP][5];

    // ---- 0. zero-slice of the zero region (consumed by k_dk/k_fix5/k_fba) ----
    if (blockIdx.x < NZ_BLK) {
        int z = blockIdx.x * 256 + j;
        if (z < zn) zbase[z] = 0ull;
    }

    // ---- 1. per-column params (same expressions as old k_pre prm branch) ----
    const float* g = gtb + ((size_t)(b * GN + j)) * 4;
    const float g0 = g[0], g1 = g[1], g2 = g[2], g3 = g[3];
    const float* it = imgt + ((size_t)(b * GN + j)) * 4;
    const float gn0 = g0 / it[0], gn1 = g1 / it[1], gn2 = g2 / it[2], gn3 = g3 / it[3];
    const float t0 = gtt[(b * GN + j) * 3 + 0], t1 = gtt[(b * GN + j) * 3 + 1],
                t2 = gtt[(b * GN + j) * 3 + 2];
    const float r0 = gtr[(b * GN + j) * 3 + 0], r1 = gtr[(b * GN + j) * 3 + 1],
                r2 = gtr[(b * GN + j) * 3 + 2];
    const float ga = (g2 - g0) * (g3 - g1);
    {
        float gcx = (g0 + g2) * 0.5f, gcy = (g1 + g3) * 0.5f;
        float gw = g2 - g0, gh = g3 - g1;
        float X0 = gcx - gw * 0.5f, Y0 = gcy - gh * 0.5f;
        float X1 = gcx + gw * 0.5f, Y1 = gcy + gh * 0.5f;
        float Wd = X1 - X0, Hd = Y1 - Y0;
        Lb[0 * GN + j] = X0;  Lb[1 * GN + j] = Y0;
        Lb[2 * GN + j] = X1;  Lb[3 * GN + j] = Y1;
        Lb[4 * GN + j] = gcx - 2.5f * Wd; Lb[5 * GN + j] = gcx + 2.5f * Wd;
        Lb[6 * GN + j] = gcy - 2.5f * Hd; Lb[7 * GN + j] = gcy + 2.5f * Hd;
    }
    const int lab = labels[b * GN + j];

    // ---- 2. class focal for the block's 32 rows x 80 classes (contiguous 10 KB span) ----
    const float* lbase = logits + ((size_t)(b * QN + i0)) * CN;
#pragma unroll
    for (int q = 0; q < 10; q++) {
        int idx = q * 256 + j;
        float x = lbase[idx];
        float e = (float)exp(-(double)x);
        float pr = 1.0f / (1.0f + e);
        float om = 1.0f - pr;
        float lneg = (float)log((double)(om + 1e-8f));
        float lpos = (float)log((double)(pr + 1e-8f));
        float neg = (0.75f * (pr * pr)) * (-lneg);
        float pos = (0.25f * (om * om)) * (-lpos);
        Lc[idx] = pos - neg;
    }

    // ---- 3. row staging ----
    if (threadIdx.x < RPP) {
        const int i = i0 + threadIdx.x;
        const float im0 = img[b * 4 + 0], im1 = img[b * 4 + 1];
        const float im2 = img[b * 4 + 2], im3 = img[b * 4 + 3];
        const float4 bx = *reinterpret_cast<const float4*>(pboxes + ((size_t)(b * QN + i)) * 4);
        const float b0 = bx.x, b1 = bx.y, b2 = bx.z, b3 = bx.w;
        const float2* pp2 = reinterpret_cast<const float2*>(pposes + ((size_t)(b * QN + i)) * 6);
        const float2 q0 = pp2[0], q1 = pp2[1], q2 = pp2[2];
        const float bn0 = b0 / im0, bn1 = b1 / im1, bn2 = b2 / im2, bn3 = b3 / im3;
        const float a1 = (b2 - b0) * (b3 - b1);
        const float ax = (b0 + b2) * 0.5f, ay = (b1 + b3) * 0.5f;
        Rsh[threadIdx.x][0] = make_float4(b0, b1, b2, b3);
        Rsh[threadIdx.x][1] = make_float4(bn0, bn1, bn2, bn3);
        Rsh[threadIdx.x][2] = make_float4(ax, ay, a1, 0.0f);
        Rsh[threadIdx.x][3] = make_float4(q0.x, q0.y, q1.x, q1.y);
        Rsh[threadIdx.x][4] = make_float4(q2.x, q2.y, 0.0f, 0.0f);
    }
    __syncthreads();

    // ---- 4. fg: thread t -> row t&31, gt chunk t>>5 (32 gts), partial OR of (ib|ic) ----
    {
        const int r = threadIdx.x & 31, ch = threadIdx.x >> 5;
        const float axr = Rsh[r][2].x, ayr = Rsh[r][2].y;
        bool any = false;
        const int jb = ch * 32;
#pragma unroll 8
        for (int m = 0; m < 32; m++) {
            int jj = jb + m;
            bool ib = (axr > Lb[0 * GN + jj]) && (axr < Lb[2 * GN + jj]) &&
                      (ayr > Lb[1 * GN + jj]) && (ayr < Lb[3 * GN + jj]);
            bool ic = (axr > Lb[4 * GN + jj]) && (axr < Lb[5 * GN + jj]) &&
                      (ayr > Lb[6 * GN + jj]) && (ayr < Lb[7 * GN + jj]);
            any |= (ib || ic);
        }
        Lfg[r * 8 + ch] = any ? 1u : 0u;
    }
    __syncthreads();
    if (threadIdx.x < RPP) {
        unsigned int a = 0;
#pragma unroll
        for (int c = 0; c < 8; c++) a |= Lfg[threadIdx.x * 8 + c];
        fgf[threadIdx.x] = a ? 0.0f : 10000.0f;
    }
    __syncthreads();

    // ---- 5. cost + selection main loop ----
    const float X0 = Lb[0 * GN + j], Y0 = Lb[1 * GN + j];
    const float X1 = Lb[2 * GN + j], Y1 = Lb[3 * GN + j];
    const float LOX = Lb[4 * GN + j], HIX = Lb[5 * GN + j];
    const float LOY = Lb[6 * GN + j], HIY = Lb[7 * GN + j];
    float* CT = costT + ((size_t)(b * QN) + i0) * GN + j;

    u64 ck[5]; float iv[5];
#pragma unroll
    for (int k = 0; k < 5; k++) { ck[k] = ~0ull; iv[k] = -1.0f; }

    for (int r = 0; r < RPP; r++) {
        const int i = i0 + r;
        const float4 R0 = Rsh[r][0];
        const float4 R1 = Rsh[r][1];
        const float4 R2 = Rsh[r][2];
        const float4 R3 = Rsh[r][3];
        const float4 R4 = Rsh[r][4];
        const float b0 = R0.x, b1 = R0.y, b2 = R0.z, b3 = R0.w;
        const float bn0 = R1.x, bn1 = R1.y, bn2 = R1.z, bn3 = R1.w;
        const float ax = R2.x, ay = R2.y, a1 = R2.z;
        const float fgadd = fgf[r];
        const float p0 = R3.x, p1 = R3.y, p2 = R3.z, p3 = R3.w;
        const float p4 = R4.x, p5 = R4.y;
        const float cc = Lc[r * CN + lab];

        // iou / giou (f32, reference op order)
        float ltx = fmaxf(b0, g0), lty = fmaxf(b1, g1);
        float rbx = fminf(b2, g2), rby = fminf(b3, g3);
        float w = fmaxf(rbx - ltx, 0.0f), h = fmaxf(rby - lty, 0.0f);
        float inter = w * h;
        float uni = (a1 + ga) - inter;
        float iou = inter / uni;
        float eltx = fminf(b0, g0), elty = fminf(b1, g1);
        float erbx = fmaxf(b2, g2), erby = fmaxf(b3, g3);
        float ew = fmaxf(erbx - eltx, 0.0f), eh = fmaxf(erby - elty, 0.0f);
        float earea = ew * eh;
        float giou = iou - (earea - uni) / earea;

        // normalized bbox L1 (sequential f32)
        float cb = fabsf(bn0 - gn0);
        cb = cb + fabsf(bn1 - gn1);
        cb = cb + fabsf(bn2 - gn2);
        cb = cb + fabsf(bn3 - gn3);
        // pose L1
        float ct = fabsf(p0 - t0); ct = ct + fabsf(p1 - t1); ct = ct + fabsf(p2 - t2);
        float cr = fabsf(p3 - r0); cr = cr + fabsf(p4 - r1); cr = cr + fabsf(p5 - r2);
        // both
        bool ib = (ax > X0) && (ax < X1) && (ay > Y0) && (ay < Y1);
        bool ic = (ax > LOX) && (ax < HIX) && (ay > LOY) && (ay < HIY);
        bool nb = !(ib && ic);

        float d = 5.0f * cb;
        d = d + 2.0f * cc;
        d = d + 2.0f * (-giou);
        d = d + (nb ? 100.0f : 0.0f);
        d = d + ct;
        d = d + cr;
        d = d + fgadd;

        CT[(size_t)r * GN] = d;

        // bottom-5 via u64 key cascade (order-isomorphic to (cost,i) lex)
        u64 key = ((u64)fkey(d) << 32) | (unsigned int)i;
        if (key < ck[4]) {
#pragma unroll
            for (int k = 0; k < 5; k++) {
                u64 mn = key < ck[k] ? key : ck[k];
                u64 mx = key < ck[k] ? ck[k] : key;
                ck[k] = mn; key = mx;
            }
        }
        // top-5 iou via max/min network
        if (iou > iv[4]) {
            float fv = iou;
#pragma unroll
            for (int k = 0; k < 5; k++) {
                float mx = fmaxf(fv, iv[k]);
                fv = fminf(fv, iv[k]);
                iv[k] = mx;
            }
        }
    }

    // pack one 64B record and store as 4x16B (full-line write)
    const int col = b * GN + j;
    u64 buf[8];
#pragma unroll
    for (int k = 0; k < 5; k++) buf[k] = ck[k];
    float* bf = (float*)(buf + 5);
#pragma unroll
    for (int k = 0; k < 5; k++) bf[k] = iv[k];
    bf[5] = 0.0f;                                   // pad -> full 64B line
    ulonglong2* dst = (ulonglong2*)(rec + (((size_t)col * NPART) + part) * 8);
    const ulonglong2* src = (const ulonglong2*)buf;
    dst[0] = src[0]; dst[1] = src[1]; dst[2] = src[2]; dst[3] = src[3];
}

// ---------------- merge parts (wave butterfly), dk, rowmask, rowcnt, amin/staleAmin init ----
__global__ __launch_bounds__(256) void k_dk(const u64* __restrict__ rec,
                                            float* __restrict__ candcv, int* __restrict__ candci,
                                            int* __restrict__ dkArr, u64* __restrict__ rowmask,
                                            u64* __restrict__ amin, int* __restrict__ rowcnt,
                                            u64* __restrict__ staleAmin) {
#pragma clang fp contract(off)
    const int lane = threadIdx.x & 63;
    const int colIdx = blockIdx.x * 4 + (threadIdx.x >> 6);   // 4 waves/block
    const int b = colIdx >> 8, j = colIdx & 255;
    // rec[col][part]: wave reads parts lane and lane+64 -> two contiguous 4KiB spans
    const u64* R0 = rec + (((size_t)colIdx * NPART) + lane) * 8;
    const u64* R1 = R0 + 64 * 8;
    u64 rv[5]; float fr[5];
    const float* F0 = (const float*)(R0 + 5);
#pragma unroll
    for (int k = 0; k < 5; k++) { rv[k] = R0[k]; fr[k] = F0[k]; }
    const float* F1 = (const float*)(R1 + 5);
#pragma unroll
    for (int m = 0; m < 5; m++) {
        u64 key = R1[m];
        if (key < rv[4]) {
#pragma unroll
            for (int k = 0; k < 5; k++) {
                u64 mn = key < rv[k] ? key : rv[k];
                u64 mx = key < rv[k] ? rv[k] : key;
                rv[k] = mn; key = mx;
            }
        }
        float fv = F1[m];
        if (fv > fr[4]) {
#pragma unroll
            for (int k = 0; k < 5; k++) {
                float mx = fmaxf(fv, fr[k]);
                fv = fminf(fv, fr[k]);
                fr[k] = mx;
            }
        }
    }
    for (int off = 1; off < 64; off <<= 1) {
        u64 ov[5]; float of[5];
#pragma unroll
        for (int m = 0; m < 5; m++) {
            ov[m] = __shfl_xor(rv[m], off, 64);
            of[m] = __shfl_xor(fr[m], off, 64);
        }
#pragma unroll
        for (int m = 0; m < 5; m++) {
            u64 key = ov[m];
            if (key < rv[4]) {
#pragma unroll
                for (int k = 0; k < 5; k++) {
                    u64 mn = key < rv[k] ? key : rv[k];
                    u64 mx = key < rv[k] ? rv[k] : key;
                    rv[k] = mn; key = mx;
                }
            }
            float fv = of[m];
            if (fv > fr[4]) {
#pragma unroll
                for (int k = 0; k < 5; k++) {
                    float mx = fmaxf(fv, fr[k]);
                    fv = fminf(fv, fr[k]);
                    fr[k] = mx;
                }
            }
        }
    }

    if (lane == 0) {
        float sum = ((((fr[0] + fr[1]) + fr[2]) + fr[3]) + fr[4]);  // desc order, sequential
        int dk = (int)sum;
        if (dk < 1) dk = 1;
        if (dk > 5) dk = 5;
        dkArr[colIdx] = dk;
        amin[colIdx] = ~0ull;
        staleAmin[colIdx] = ~0ull;
#pragma unroll
        for (int k = 0; k < 5; k++) {
            candcv[(size_t)colIdx * 5 + k] = funkey((unsigned int)(rv[k] >> 32));
            candci[(size_t)colIdx * 5 + k] = (int)(unsigned int)(rv[k] & 0xFFFFFFFFull);
        }
        for (int k = 0; k < dk; k++) {
            int i = (int)(unsigned int)(rv[k] & 0xFFFFFFFFull);
            atomicOr(&rowmask[((size_t)(b * QN + i)) * 4 + (j >> 6)], 1ull << (j & 63));
            atomicAdd(&rowcnt[b * QN + i], 1);
        }
    }
}

// ---------------- fused: detect+wave-fix+colcnt (blocks 0..255) | candidate-assign (256..271) ----
__global__ __launch_bounds__(256) void k_fix5(const float* __restrict__ costT,
                                              u64* __restrict__ rowmask,
                                              int* __restrict__ colcnt,
                                              const int* __restrict__ rowcnt,
                                              const float* __restrict__ candcv,
                                              const int* __restrict__ candci,
                                              u64* __restrict__ amin,
                                              u64* __restrict__ staleAmin,
                                              int* __restrict__ fbCount,
                                              int* __restrict__ fbL) {
    if (blockIdx.x < 256) {
        // ---- row side: per-thread detect, wave-cooperative fix ----
        const int b = blockIdx.x >> 4;
        const int i = (blockIdx.x & 15) * 256 + threadIdx.x;
        const int lane = threadIdx.x & 63;
        const int cnt = rowcnt[b * QN + i];
        if (cnt == 1) {
            const u64* rm = rowmask + ((size_t)(b * QN + i)) * 4;
            u64 w0 = rm[0], w1 = rm[1], w2 = rm[2], w3 = rm[3];
            u64 w; int base;
            if (w0) { w = w0; base = 0; }
            else if (w1) { w = w1; base = 64; }
            else if (w2) { w = w2; base = 128; }
            else { w = w3; base = 192; }
            int jj = base + (__ffsll((long long)w) - 1);
            atomicAdd(&colcnt[b * GN + jj], 1);
        }
        // wave-cooperative fix of flagged (stale) rows, one at a time
        u64 bal = __ballot(cnt > 1);
        while (bal) {
            const int L = __ffsll((long long)bal) - 1;
            bal &= bal - 1;
            const int iL = (i & ~63) | L;
            const float* cb = costT + ((size_t)(b * QN) + iL) * GN;   // contiguous row
            float best = FLT_MAX; int bj = GN;
            for (int k = 0; k < GN; k += 64) {
                int jj = k + lane;
                float v = cb[jj];
                if (lexLessF(v, jj, best, bj)) { best = v; bj = jj; }
            }
            for (int off = 32; off > 0; off >>= 1) {
                float ov = __shfl_down(best, off, 64);
                int oj = __shfl_down(bj, off, 64);
                if (lexLessF(ov, oj, best, bj)) { best = ov; bj = oj; }
            }
            if (lane == 0) {
                u64* rm = rowmask + ((size_t)(b * QN + iL)) * 4;
                rm[0] = ((bj >> 6) == 0) ? (1ull << (bj & 63)) : 0ull;
                rm[1] = ((bj >> 6) == 1) ? (1ull << (bj & 63)) : 0ull;
                rm[2] = ((bj >> 6) == 2) ? (1ull << (bj & 63)) : 0ull;
                rm[3] = ((bj >> 6) == 3) ? (1ull << (bj & 63)) : 0ull;
                atomicAdd(&colcnt[b * GN + bj], 1);
                // record stale winner for k_out: pv = best + 100000, tie-break by row index
                float pv = best + 100000.0f;
                u64 key = ((u64)fkey(pv) << 32) | (unsigned int)iL;
                atomicMin(&staleAmin[b * GN + bj], key);
            }
        }
        return;
    }

    // ---- candidate-based assign: 16 blocks, 1 thread/column ----
    const int b = blockIdx.x - 256;
    const int j = threadIdx.x;
    const int col = b * GN + j;

    if (colcnt[col] == 0) {   // racy read; monotone => spurious work discarded later
        bool found = false;
        u64 best = ~0ull;
#pragma unroll
        for (int k = 0; k < 5; k++) {
            if (!found) {
                int i = candci[(size_t)col * 5 + k];
                if (rowcnt[b * QN + i] == 0) {
                    best = ((u64)fkey(candcv[(size_t)col * 5 + k]) << 32) | (unsigned int)i;
                    found = true;
                }
            }
        }
        if (found) {
            amin[col] = best;
        } else {
            int e = atomicAdd(fbCount, 1);   // rare: resolve in k_fba with full parallelism
            fbL[e] = col;
        }
    }
}

// ---------------- fused: assign-finalize (blocks 0..15) | fallback scans (blocks 16..271) ----
__global__ __launch_bounds__(256) void k_fba(const float* __restrict__ costT,
                                             const int* __restrict__ rowcnt,
                                             const int* __restrict__ colcnt,
                                             const u64* __restrict__ amin,
                                             const int* __restrict__ fbCount,
                                             const int* __restrict__ fbL,
                                             int* __restrict__ assign,
                                             u64* __restrict__ rowmask) {
    if (blockIdx.x < BN) {
        const int b = blockIdx.x;
        const int j = threadIdx.x;
        const int col = b * GN + j;
        if (colcnt[col] != 0) { assign[col] = -1; return; }
        u64 key = amin[col];
        if (key == ~0ull) return;            // fallback column: handled by scan blocks
        int r = (int)(unsigned int)(key & 0xFFFFFFFFull);
        assign[col] = r;
        atomicOr(&rowmask[((size_t)(b * QN + r)) * 4 + (j >> 6)], 1ull << (j & 63));
        return;
    }
    // ---- fallback scans ----
    __shared__ u64 red[256];
    const int n = *fbCount;
    const int t = threadIdx.x;
    for (int e = blockIdx.x - BN; e < n; e += 256) {
        const int col = fbL[e];
        const int b = col >> 8, j = col & 255;
        if (colcnt[col] != 0) continue;      // spuriously recorded; assign=-1 already written
        const float* C = costT + ((size_t)(b * QN)) * GN + j;
        const int* rc = rowcnt + b * QN;
        u64 best = ~0ull;
#pragma unroll
        for (int s = 0; s < 16; s++) {
            int r = s * 256 + t;
            if (rc[r] == 0) {
                float v = C[(size_t)r * GN];
                u64 key = ((u64)fkey(v) << 32) | (unsigned int)r;
                best = key < best ? key : best;
            }
        }
        red[t] = best;
        __syncthreads();
        for (int s2 = 128; s2 > 0; s2 >>= 1) {
            if (t < s2) { u64 o = red[t + s2]; if (o < red[t]) red[t] = o; }
            __syncthreads();
        }
        if (t == 0) {
            int r = (int)(unsigned int)(red[0] & 0xFFFFFFFFull);
            assign[col] = r;
            atomicOr(&rowmask[((size_t)(b * QN + r)) * 4 + (j >> 6)], 1ull << (j & 63));
        }
        __syncthreads();   // red reused next iteration
    }
}

// ---------------- fused outputs: outrows (blocks 0..255) | outcols (256..271) ----------------
__global__ __launch_bounds__(256) void k_out(const u64* __restrict__ rowmask,
                                             const int* __restrict__ assign,
                                             const float* __restrict__ candcv,
                                             const int* __restrict__ candci,
                                             const int* __restrict__ dkArr,
                                             const u64* __restrict__ staleAmin,
                                             int* __restrict__ out) {
    if (blockIdx.x < 256) {
        // ---- outrows ----
        const int b = blockIdx.x >> 4;
        const int i = (blockIdx.x & 15) * 256 + threadIdx.x;
        const u64* rm = rowmask + ((size_t)(b * QN + i)) * 4;
        u64 w0 = rm[0], w1 = rm[1], w2 = rm[2], w3 = rm[3];
        int sel = (w0 | w1 | w2 | w3) ? 1 : 0;
        int g = 0;
        if (w0) g = __ffsll((long long)w0) - 1;
        else if (w1) g = 64 + __ffsll((long long)w1) - 1;
        else if (w2) g = 128 + __ffsll((long long)w2) - 1;
        else if (w3) g = 192 + __ffsll((long long)w3) - 1;
        out[(size_t)b * QN + i] = sel;
        out[(size_t)BN * QN + (size_t)b * QN + i] = g;
        return;
    }
    // ---- outcols ----
    const int b = blockIdx.x - 256;
    const int j = threadIdx.x;
    const int col = b * GN + j;
    int* o = out + (size_t)2 * BN * QN + col;
    int a = assign[col];
    if (a >= 0) { *o = a; return; }
    const u64 bit = 1ull << (j & 63);
    const int w = j >> 6;
    float best = FLT_MAX; int bi = INT_MAX;
    const int dk = dkArr[col];
    for (int k = 0; k < 5; k++) {
        if (k < dk) {
            int i = candci[(size_t)col * 5 + k];
            if (rowmask[((size_t)(b * QN + i)) * 4 + w] & bit) {
                float pv = candcv[(size_t)col * 5 + k] + 100000.0f;
                if (lexLessF(pv, i, best, bi)) { best = pv; bi = i; }
            }
        }
    }
    // stale winner for this column (lex-min over all stale rows fixed to j), one read
    const u64 sk = staleAmin[col];
    if (sk != ~0ull) {
        float pv = funkey((unsigned int)(sk >> 32));
        int ei = (int)(unsigned int)(sk & 0xFFFFFFFFull);
        if (lexLessF(pv, ei, best, bi)) { best = pv; bi = ei; }
    }
    *o = (bi == INT_MAX) ? 0 : bi;
}

extern "C" void kernel_launch(void* const* d_in, const int* in_sizes, int n_in,
                              void* d_out, int out_size, void* d_ws, size_t ws_size,
                              hipStream_t stream) {
    const float* logits = (const float*)d_in[0];
    const float* pboxes = (const float*)d_in[1];
    const float* pposes = (const float*)d_in[2];
    const int* labels = (const int*)d_in[3];
    const float* gtb = (const float*)d_in[4];
    const float* gtt = (const float*)d_in[5];
    const float* gtr = (const float*)d_in[6];
    const float* img = (const float*)d_in[7];
    const float* imgt = (const float*)d_in[8];
    int* out = (int*)d_out;

    char* p = (char*)d_ws;
    float* costT = (float*)p;            p += (size_t)BN * QN * GN * 4;        // 64 MiB
    u64* rec = (u64*)p;                  p += (size_t)BN * GN * NPART * 64;    // 32 MiB (64B/record)
    // ---- zero region: rowmask | colcnt | fbCount | rowcnt (contiguous) ----
    u64* rowmask = (u64*)p;              size_t rb = (size_t)BN * QN * 4 * 8; p += rb;  // 2 MiB
    int* colcnt = (int*)p;               p += (size_t)BN * GN * 4;             // 16 KiB
    int* fbCount = (int*)p;              p += 64;
    int* rowcnt = (int*)p;               p += (size_t)BN * QN * 4;             // 256 KiB
    // ---- end zero region ----
    int* assign = (int*)p;               p += (size_t)BN * GN * 4;             // 16 KiB
    float* candcv = (float*)p;           p += (size_t)BN * GN * 5 * 4;         // 80 KiB
    int* candci = (int*)p;               p += (size_t)BN * GN * 5 * 4;         // 80 KiB
    int* dkArr = (int*)p;                p += (size_t)BN * GN * 4;             // 16 KiB
    u64* amin = (u64*)p;                 p += (size_t)BN * GN * 8;             // 32 KiB
    u64* staleAmin = (u64*)p;            p += (size_t)BN * GN * 8;             // 32 KiB (init in k_dk)
    int* fbL = (int*)p;                  p += (size_t)BN * GN * 4;             // 16 KiB

    // zero region size in u64: rowmask(2MiB) + colcnt(16KiB) + 64B + rowcnt(256KiB)
    int zn = (int)((rb + (size_t)BN * GN * 4 + 64 + (size_t)BN * QN * 4) / 8);  // = 296968

    k_main<<<BN * NPART, 256, 0, stream>>>(logits, labels, gtb, gtt, gtr, imgt,
                                           pboxes, pposes, img, costT, rec,
                                           (u64*)rowmask, zn);
    k_dk<<<BN * GN / 4, 256, 0, stream>>>(rec, candcv, candci, dkArr, rowmask, amin, rowcnt,
                                          staleAmin);
    k_fix5<<<256 + BN, 256, 0, stream>>>(costT, rowmask, colcnt, rowcnt, candcv, candci,
                                         amin, staleAmin, fbCount, fbL);
    k_fba<<<BN + 256, 256, 0, stream>>>(costT, rowcnt, colcnt, amin, fbCount, fbL,
                                        assign, rowmask);
    k_out<<<256 + BN, 256, 0, stream>>>(rowmask, assign, candcv, candci, dkArr, staleAmin, out);
}

// Round 12
// 211.866 us; speedup vs baseline: 1.7314x; 1.0314x over previous
//
#include <hip/hip_runtime.h>
#include <cfloat>
#include <climits>
#include <math.h>

#define BN 16
#define QN 4096
#define GN 256
#define CN 80
#define NPART 64           // row parts in k_main (64 rows each)
#define RPP (QN / NPART)   // 64

typedef unsigned long long u64;

__device__ __forceinline__ bool lexLessF(float a, int ia, float b, int ib) {
    return (a < b) || (a == b && ia < ib);
}
// IEEE order-isomorphic u32 key (no NaNs in this data)
__device__ __forceinline__ unsigned int fkey(float f) {
    unsigned int b = __float_as_uint(f);
    return b ^ ((b >> 31) ? 0xFFFFFFFFu : 0x80000000u);
}
__device__ __forceinline__ float funkey(unsigned int k) {
    unsigned int b = k ^ ((k >> 31) ? 0x80000000u : 0xFFFFFFFFu);
    return __uint_as_float(b);
}

// ---------------- fully-fused front-end: zero | prm | class | fg | cost | selection ----------
// Each block owns rows i0..i0+63 of batch b exclusively. All numerics identical expressions
// (contract off) -> bit-identical costs. fg phase emits a both-bitmask so the main loop does
// NOT recompute the 8 bounds compares per cell. Lc stores 2*cc (exact f32 doubling).
__global__ __launch_bounds__(256) void k_main(
    const float* __restrict__ logits, const int* __restrict__ labels,
    const float* __restrict__ gtb, const float* __restrict__ gtt,
    const float* __restrict__ gtr, const float* __restrict__ imgt,
    const float* __restrict__ pboxes, const float* __restrict__ pposes,
    const float* __restrict__ img,
    float* __restrict__ costT, u64* __restrict__ rec,
    u64* __restrict__ zbase, int zn) {
#pragma clang fp contract(off)
    const int j = threadIdx.x;
    const int b = blockIdx.x >> 6;
    const int part = blockIdx.x & 63;
    const int i0 = part * RPP;

    __shared__ float Lc[RPP * CN];       // 64x80 2x focal class costs (20.5 KB)
    __shared__ float Lb[8 * GN];         // X0,Y0,X1,Y1,LOX,HIX,LOY,HIY per column (8 KB)
    __shared__ u64 Lboth[RPP][4];        // both-bitmask per row (2 KB)
    __shared__ unsigned int Lany[RPP * 4];
    __shared__ float4 Rsh[RPP][5];

    // ---- 0. zero-slice of the zero region (consumed by k_dk/k_fix5/k_fba) ----
    for (int z = blockIdx.x * 256 + j; z < zn; z += 1024 * 256) zbase[z] = 0ull;

    // ---- 1. per-column params (identical expressions) ----
    const float* g = gtb + ((size_t)(b * GN + j)) * 4;
    const float g0 = g[0], g1 = g[1], g2 = g[2], g3 = g[3];
    const float* it = imgt + ((size_t)(b * GN + j)) * 4;
    const float gn0 = g0 / it[0], gn1 = g1 / it[1], gn2 = g2 / it[2], gn3 = g3 / it[3];
    const float t0 = gtt[(b * GN + j) * 3 + 0], t1 = gtt[(b * GN + j) * 3 + 1],
                t2 = gtt[(b * GN + j) * 3 + 2];
    const float r0 = gtr[(b * GN + j) * 3 + 0], r1 = gtr[(b * GN + j) * 3 + 1],
                r2 = gtr[(b * GN + j) * 3 + 2];
    const float ga = (g2 - g0) * (g3 - g1);
    {
        float gcx = (g0 + g2) * 0.5f, gcy = (g1 + g3) * 0.5f;
        float gw = g2 - g0, gh = g3 - g1;
        float X0 = gcx - gw * 0.5f, Y0 = gcy - gh * 0.5f;
        float X1 = gcx + gw * 0.5f, Y1 = gcy + gh * 0.5f;
        float Wd = X1 - X0, Hd = Y1 - Y0;
        Lb[0 * GN + j] = X0;  Lb[1 * GN + j] = Y0;
        Lb[2 * GN + j] = X1;  Lb[3 * GN + j] = Y1;
        Lb[4 * GN + j] = gcx - 2.5f * Wd; Lb[5 * GN + j] = gcx + 2.5f * Wd;
        Lb[6 * GN + j] = gcy - 2.5f * Hd; Lb[7 * GN + j] = gcy + 2.5f * Hd;
    }
    const int lab = labels[b * GN + j];

    // ---- 2. class focal for the block's 64 rows x 80 classes (contiguous 20 KB span) ----
    const float* lbase = logits + ((size_t)(b * QN + i0)) * CN;
#pragma unroll
    for (int q = 0; q < 20; q++) {
        int idx = q * 256 + j;
        float x = lbase[idx];
        float e = (float)exp(-(double)x);
        float pr = 1.0f / (1.0f + e);
        float om = 1.0f - pr;
        float lneg = (float)log((double)(om + 1e-8f));
        float lpos = (float)log((double)(pr + 1e-8f));
        float neg = (0.75f * (pr * pr)) * (-lneg);
        float pos = (0.25f * (om * om)) * (-lpos);
        Lc[idx] = 2.0f * (pos - neg);    // pre-doubled: 2*cc is exact in f32
    }

    // ---- 3. row staging ----
    if (threadIdx.x < RPP) {
        const int i = i0 + threadIdx.x;
        const float im0 = img[b * 4 + 0], im1 = img[b * 4 + 1];
        const float im2 = img[b * 4 + 2], im3 = img[b * 4 + 3];
        const float4 bx = *reinterpret_cast<const float4*>(pboxes + ((size_t)(b * QN + i)) * 4);
        const float b0 = bx.x, b1 = bx.y, b2 = bx.z, b3 = bx.w;
        const float2* pp2 = reinterpret_cast<const float2*>(pposes + ((size_t)(b * QN + i)) * 6);
        const float2 q0 = pp2[0], q1 = pp2[1], q2 = pp2[2];
        const float bn0 = b0 / im0, bn1 = b1 / im1, bn2 = b2 / im2, bn3 = b3 / im3;
        const float a1 = (b2 - b0) * (b3 - b1);
        const float ax = (b0 + b2) * 0.5f, ay = (b1 + b3) * 0.5f;
        Rsh[threadIdx.x][0] = make_float4(b0, b1, b2, b3);
        Rsh[threadIdx.x][1] = make_float4(bn0, bn1, bn2, bn3);
        Rsh[threadIdx.x][2] = make_float4(ax, ay, a1, 0.0f);
        Rsh[threadIdx.x][3] = make_float4(q0.x, q0.y, q1.x, q1.y);
        Rsh[threadIdx.x][4] = make_float4(q2.x, q2.y, 0.0f, 0.0f);
    }
    __syncthreads();

    // ---- 4. fg + both-bits: thread t -> row t&63, gt chunk t>>6 (64 gts) ----
    {
        const int r = threadIdx.x & 63, ch = threadIdx.x >> 6;
        const float axr = Rsh[r][2].x, ayr = Rsh[r][2].y;
        bool any = false;
        u64 bothbits = 0;
        const int jb = ch * 64;
#pragma unroll 8
        for (int m = 0; m < 64; m++) {
            int jj = jb + m;
            bool ib = (axr > Lb[0 * GN + jj]) && (axr < Lb[2 * GN + jj]) &&
                      (ayr > Lb[1 * GN + jj]) && (ayr < Lb[3 * GN + jj]);
            bool ic = (axr > Lb[4 * GN + jj]) && (axr < Lb[5 * GN + jj]) &&
                      (ayr > Lb[6 * GN + jj]) && (ayr < Lb[7 * GN + jj]);
            any |= (ib || ic);
            if (ib && ic) bothbits |= (1ull << m);
        }
        Lany[r * 4 + ch] = any ? 1u : 0u;
        Lboth[r][ch] = bothbits;
    }
    __syncthreads();
    if (threadIdx.x < RPP) {
        unsigned int a = 0;
#pragma unroll
        for (int c = 0; c < 4; c++) a |= Lany[threadIdx.x * 4 + c];
        Rsh[threadIdx.x][2].w = a ? 0.0f : 10000.0f;   // fgadd folded into row record
    }
    __syncthreads();

    // ---- 5. cost + selection main loop ----
    float* CT = costT + ((size_t)(b * QN) + i0) * GN + j;
    const int jw = j >> 6, jb63 = j & 63;

    u64 ck[5]; float iv[5];
#pragma unroll
    for (int k = 0; k < 5; k++) { ck[k] = ~0ull; iv[k] = -1.0f; }

    for (int r = 0; r < RPP; r++) {
        const int i = i0 + r;
        const float4 R0 = Rsh[r][0];
        const float4 R1 = Rsh[r][1];
        const float4 R2 = Rsh[r][2];
        const float4 R3 = Rsh[r][3];
        const float4 R4 = Rsh[r][4];
        const float b0 = R0.x, b1 = R0.y, b2 = R0.z, b3 = R0.w;
        const float bn0 = R1.x, bn1 = R1.y, bn2 = R1.z, bn3 = R1.w;
        const float a1 = R2.z, fgadd = R2.w;
        const float p0 = R3.x, p1 = R3.y, p2 = R3.z, p3 = R3.w;
        const float p4 = R4.x, p5 = R4.y;
        const float cc2 = Lc[r * CN + lab];
        const bool both = (Lboth[r][jw] >> jb63) & 1;

        // iou / giou (f32, reference op order)
        float ltx = fmaxf(b0, g0), lty = fmaxf(b1, g1);
        float rbx = fminf(b2, g2), rby = fminf(b3, g3);
        float w = fmaxf(rbx - ltx, 0.0f), h = fmaxf(rby - lty, 0.0f);
        float inter = w * h;
        float uni = (a1 + ga) - inter;
        float iou = inter / uni;
        float eltx = fminf(b0, g0), elty = fminf(b1, g1);
        float erbx = fmaxf(b2, g2), erby = fmaxf(b3, g3);
        float ew = fmaxf(erbx - eltx, 0.0f), eh = fmaxf(erby - elty, 0.0f);
        float earea = ew * eh;
        float giou = iou - (earea - uni) / earea;

        // normalized bbox L1 (sequential f32)
        float cb = fabsf(bn0 - gn0);
        cb = cb + fabsf(bn1 - gn1);
        cb = cb + fabsf(bn2 - gn2);
        cb = cb + fabsf(bn3 - gn3);
        // pose L1
        float ct = fabsf(p0 - t0); ct = ct + fabsf(p1 - t1); ct = ct + fabsf(p2 - t2);
        float cr = fabsf(p3 - r0); cr = cr + fabsf(p4 - r1); cr = cr + fabsf(p5 - r2);

        float d = 5.0f * cb;
        d = d + cc2;
        d = d + 2.0f * (-giou);
        d = d + (both ? 0.0f : 100.0f);
        d = d + ct;
        d = d + cr;
        d = d + fgadd;

        CT[(size_t)r * GN] = d;

        // bottom-5 via u64 key cascade (order-isomorphic to (cost,i) lex)
        u64 key = ((u64)fkey(d) << 32) | (unsigned int)i;
        if (key < ck[4]) {
#pragma unroll
            for (int k = 0; k < 5; k++) {
                u64 mn = key < ck[k] ? key : ck[k];
                u64 mx = key < ck[k] ? ck[k] : key;
                ck[k] = mn; key = mx;
            }
        }
        // top-5 iou via max/min network
        if (iou > iv[4]) {
            float fv = iou;
#pragma unroll
            for (int k = 0; k < 5; k++) {
                float mx = fmaxf(fv, iv[k]);
                fv = fminf(fv, iv[k]);
                iv[k] = mx;
            }
        }
    }

    // pack one 64B record and store as 4x16B (full-line write)
    const int col = b * GN + j;
    u64 buf[8];
#pragma unroll
    for (int k = 0; k < 5; k++) buf[k] = ck[k];
    float* bf = (float*)(buf + 5);
#pragma unroll
    for (int k = 0; k < 5; k++) bf[k] = iv[k];
    bf[5] = 0.0f;                                   // pad -> full 64B line
    ulonglong2* dst = (ulonglong2*)(rec + (((size_t)col * NPART) + part) * 8);
    const ulonglong2* src = (const ulonglong2*)buf;
    dst[0] = src[0]; dst[1] = src[1]; dst[2] = src[2]; dst[3] = src[3];
}

// ---------------- merge parts (wave butterfly), dk, rowmask, rowcnt, amin/staleAmin init ----
// NPART=64: exactly one record per lane; no pre-merge needed.
__global__ __launch_bounds__(256) void k_dk(const u64* __restrict__ rec,
                                            float* __restrict__ candcv, int* __restrict__ candci,
                                            int* __restrict__ dkArr, u64* __restrict__ rowmask,
                                            u64* __restrict__ amin, int* __restrict__ rowcnt,
                                            u64* __restrict__ staleAmin) {
#pragma clang fp contract(off)
    const int lane = threadIdx.x & 63;
    const int colIdx = blockIdx.x * 4 + (threadIdx.x >> 6);   // 4 waves/block
    const int b = colIdx >> 8, j = colIdx & 255;
    const u64* R0 = rec + (((size_t)colIdx * NPART) + lane) * 8;
    u64 rv[5]; float fr[5];
    const float* F0 = (const float*)(R0 + 5);
#pragma unroll
    for (int k = 0; k < 5; k++) { rv[k] = R0[k]; fr[k] = F0[k]; }
    for (int off = 1; off < 64; off <<= 1) {
        u64 ov[5]; float of[5];
#pragma unroll
        for (int m = 0; m < 5; m++) {
            ov[m] = __shfl_xor(rv[m], off, 64);
            of[m] = __shfl_xor(fr[m], off, 64);
        }
#pragma unroll
        for (int m = 0; m < 5; m++) {
            u64 key = ov[m];
            if (key < rv[4]) {
#pragma unroll
                for (int k = 0; k < 5; k++) {
                    u64 mn = key < rv[k] ? key : rv[k];
                    u64 mx = key < rv[k] ? rv[k] : key;
                    rv[k] = mn; key = mx;
                }
            }
            float fv = of[m];
            if (fv > fr[4]) {
#pragma unroll
                for (int k = 0; k < 5; k++) {
                    float mx = fmaxf(fv, fr[k]);
                    fv = fminf(fv, fr[k]);
                    fr[k] = mx;
                }
            }
        }
    }

    if (lane == 0) {
        float sum = ((((fr[0] + fr[1]) + fr[2]) + fr[3]) + fr[4]);  // desc order, sequential
        int dk = (int)sum;
        if (dk < 1) dk = 1;
        if (dk > 5) dk = 5;
        dkArr[colIdx] = dk;
        amin[colIdx] = ~0ull;
        staleAmin[colIdx] = ~0ull;
#pragma unroll
        for (int k = 0; k < 5; k++) {
            candcv[(size_t)colIdx * 5 + k] = funkey((unsigned int)(rv[k] >> 32));
            candci[(size_t)colIdx * 5 + k] = (int)(unsigned int)(rv[k] & 0xFFFFFFFFull);
        }
        for (int k = 0; k < dk; k++) {
            int i = (int)(unsigned int)(rv[k] & 0xFFFFFFFFull);
            atomicOr(&rowmask[((size_t)(b * QN + i)) * 4 + (j >> 6)], 1ull << (j & 63));
            atomicAdd(&rowcnt[b * QN + i], 1);
        }
    }
}

// ---------------- fused: detect+wave-fix+colcnt (blocks 0..255) | candidate-assign (256..271) ----
__global__ __launch_bounds__(256) void k_fix5(const float* __restrict__ costT,
                                              u64* __restrict__ rowmask,
                                              int* __restrict__ colcnt,
                                              const int* __restrict__ rowcnt,
                                              const float* __restrict__ candcv,
                                              const int* __restrict__ candci,
                                              u64* __restrict__ amin,
                                              u64* __restrict__ staleAmin,
                                              int* __restrict__ fbCount,
                                              int* __restrict__ fbL) {
    if (blockIdx.x < 256) {
        // ---- row side: per-thread detect, wave-cooperative fix ----
        const int b = blockIdx.x >> 4;
        const int i = (blockIdx.x & 15) * 256 + threadIdx.x;
        const int lane = threadIdx.x & 63;
        const int cnt = rowcnt[b * QN + i];
        if (cnt == 1) {
            const u64* rm = rowmask + ((size_t)(b * QN + i)) * 4;
            u64 w0 = rm[0], w1 = rm[1], w2 = rm[2], w3 = rm[3];
            u64 w; int base;
            if (w0) { w = w0; base = 0; }
            else if (w1) { w = w1; base = 64; }
            else if (w2) { w = w2; base = 128; }
            else { w = w3; base = 192; }
            int jj = base + (__ffsll((long long)w) - 1);
            atomicAdd(&colcnt[b * GN + jj], 1);
        }
        // wave-cooperative fix of flagged (stale) rows, one at a time
        u64 bal = __ballot(cnt > 1);
        while (bal) {
            const int L = __ffsll((long long)bal) - 1;
            bal &= bal - 1;
            const int iL = (i & ~63) | L;
            const float* cb = costT + ((size_t)(b * QN) + iL) * GN;   // contiguous row
            float best = FLT_MAX; int bj = GN;
            for (int k = 0; k < GN; k += 64) {
                int jj = k + lane;
                float v = cb[jj];
                if (lexLessF(v, jj, best, bj)) { best = v; bj = jj; }
            }
            for (int off = 32; off > 0; off >>= 1) {
                float ov = __shfl_down(best, off, 64);
                int oj = __shfl_down(bj, off, 64);
                if (lexLessF(ov, oj, best, bj)) { best = ov; bj = oj; }
            }
            if (lane == 0) {
                u64* rm = rowmask + ((size_t)(b * QN + iL)) * 4;
                rm[0] = ((bj >> 6) == 0) ? (1ull << (bj & 63)) : 0ull;
                rm[1] = ((bj >> 6) == 1) ? (1ull << (bj & 63)) : 0ull;
                rm[2] = ((bj >> 6) == 2) ? (1ull << (bj & 63)) : 0ull;
                rm[3] = ((bj >> 6) == 3) ? (1ull << (bj & 63)) : 0ull;
                atomicAdd(&colcnt[b * GN + bj], 1);
                // record stale winner for outcols: pv = best + 100000, tie-break by row index
                float pv = best + 100000.0f;
                u64 key = ((u64)fkey(pv) << 32) | (unsigned int)iL;
                atomicMin(&staleAmin[b * GN + bj], key);
            }
        }
        return;
    }

    // ---- candidate-based assign: 16 blocks, 1 thread/column ----
    const int b = blockIdx.x - 256;
    const int j = threadIdx.x;
    const int col = b * GN + j;

    if (colcnt[col] == 0) {   // racy read; monotone => spurious work discarded later
        bool found = false;
        u64 best = ~0ull;
#pragma unroll
        for (int k = 0; k < 5; k++) {
            if (!found) {
                int i = candci[(size_t)col * 5 + k];
                if (rowcnt[b * QN + i] == 0) {
                    best = ((u64)fkey(candcv[(size_t)col * 5 + k]) << 32) | (unsigned int)i;
                    found = true;
                }
            }
        }
        if (found) {
            amin[col] = best;
        } else {
            int e = atomicAdd(fbCount, 1);   // rare: resolve in k_fba with full parallelism
            fbL[e] = col;
        }
    }
}

// ---------------- fused: finalize+outcols (blocks 0..15) | fallback scans (blocks 16..271) ----
// Blocks 0..15 per column: colcnt==0 -> assignment (amin row; OR rowmask; write outcols);
// colcnt!=0 -> candidate/stale outcols (rowmask bits for matched cols are final after k_fix5;
// assignment ORs never touch matched columns' bits). Fallback cols handled by scan blocks.
__global__ __launch_bounds__(256) void k_fba(const float* __restrict__ costT,
                                             const int* __restrict__ rowcnt,
                                             const int* __restrict__ colcnt,
                                             const u64* __restrict__ amin,
                                             const int* __restrict__ fbCount,
                                             const int* __restrict__ fbL,
                                             const float* __restrict__ candcv,
                                             const int* __restrict__ candci,
                                             const int* __restrict__ dkArr,
                                             const u64* __restrict__ staleAmin,
                                             u64* __restrict__ rowmask,
                                             int* __restrict__ out) {
    if (blockIdx.x < BN) {
        const int b = blockIdx.x;
        const int j = threadIdx.x;
        const int col = b * GN + j;
        int* o = out + (size_t)2 * BN * QN + col;
        if (colcnt[col] == 0) {
            u64 key = amin[col];
            if (key == ~0ull) return;        // true fallback: scan blocks own it
            int r = (int)(unsigned int)(key & 0xFFFFFFFFull);
            atomicOr(&rowmask[((size_t)(b * QN + r)) * 4 + (j >> 6)], 1ull << (j & 63));
            *o = r;
            return;
        }
        // matched column: candidate/stale outcols
        const u64 bit = 1ull << (j & 63);
        const int w = j >> 6;
        float best = FLT_MAX; int bi = INT_MAX;
        const int dk = dkArr[col];
        for (int k = 0; k < 5; k++) {
            if (k < dk) {
                int i = candci[(size_t)col * 5 + k];
                if (rowmask[((size_t)(b * QN + i)) * 4 + w] & bit) {
                    float pv = candcv[(size_t)col * 5 + k] + 100000.0f;
                    if (lexLessF(pv, i, best, bi)) { best = pv; bi = i; }
                }
            }
        }
        const u64 sk = staleAmin[col];
        if (sk != ~0ull) {
            float pv = funkey((unsigned int)(sk >> 32));
            int ei = (int)(unsigned int)(sk & 0xFFFFFFFFull);
            if (lexLessF(pv, ei, best, bi)) { best = pv; bi = ei; }
        }
        *o = (bi == INT_MAX) ? 0 : bi;
        return;
    }
    // ---- fallback scans: one block per fbL entry (grid-stride) ----
    __shared__ u64 red[256];
    const int n = *fbCount;
    const int t = threadIdx.x;
    for (int e = blockIdx.x - BN; e < n; e += 256) {
        const int col = fbL[e];
        const int b = col >> 8, j = col & 255;
        if (colcnt[col] != 0) continue;      // spuriously recorded (outcols written by 0..15)
        const float* C = costT + ((size_t)(b * QN)) * GN + j;
        const int* rc = rowcnt + b * QN;
        u64 best = ~0ull;
#pragma unroll
        for (int s = 0; s < 16; s++) {
            int r = s * 256 + t;
            if (rc[r] == 0) {
                float v = C[(size_t)r * GN];
                u64 key = ((u64)fkey(v) << 32) | (unsigned int)r;
                best = key < best ? key : best;
            }
        }
        red[t] = best;
        __syncthreads();
        for (int s2 = 128; s2 > 0; s2 >>= 1) {
            if (t < s2) { u64 o = red[t + s2]; if (o < red[t]) red[t] = o; }
            __syncthreads();
        }
        if (t == 0) {
            int r = (int)(unsigned int)(red[0] & 0xFFFFFFFFull);
            atomicOr(&rowmask[((size_t)(b * QN + r)) * 4 + (j >> 6)], 1ull << (j & 63));
            out[(size_t)2 * BN * QN + col] = r;
        }
        __syncthreads();   // red reused next iteration
    }
}

// ---------------- outrows only (reads final rowmask) ----------------
__global__ __launch_bounds__(256) void k_out(const u64* __restrict__ rowmask,
                                             int* __restrict__ out) {
    const int b = blockIdx.x >> 4;
    const int i = (blockIdx.x & 15) * 256 + threadIdx.x;
    const u64* rm = rowmask + ((size_t)(b * QN + i)) * 4;
    u64 w0 = rm[0], w1 = rm[1], w2 = rm[2], w3 = rm[3];
    int sel = (w0 | w1 | w2 | w3) ? 1 : 0;
    int g = 0;
    if (w0) g = __ffsll((long long)w0) - 1;
    else if (w1) g = 64 + __ffsll((long long)w1) - 1;
    else if (w2) g = 128 + __ffsll((long long)w2) - 1;
    else if (w3) g = 192 + __ffsll((long long)w3) - 1;
    out[(size_t)b * QN + i] = sel;
    out[(size_t)BN * QN + (size_t)b * QN + i] = g;
}

extern "C" void kernel_launch(void* const* d_in, const int* in_sizes, int n_in,
                              void* d_out, int out_size, void* d_ws, size_t ws_size,
                              hipStream_t stream) {
    const float* logits = (const float*)d_in[0];
    const float* pboxes = (const float*)d_in[1];
    const float* pposes = (const float*)d_in[2];
    const int* labels = (const int*)d_in[3];
    const float* gtb = (const float*)d_in[4];
    const float* gtt = (const float*)d_in[5];
    const float* gtr = (const float*)d_in[6];
    const float* img = (const float*)d_in[7];
    const float* imgt = (const float*)d_in[8];
    int* out = (int*)d_out;

    char* p = (char*)d_ws;
    float* costT = (float*)p;            p += (size_t)BN * QN * GN * 4;        // 64 MiB
    u64* rec = (u64*)p;                  p += (size_t)BN * GN * NPART * 64;    // 16 MiB (64B/record)
    // ---- zero region: rowmask | colcnt | fbCount | rowcnt (contiguous) ----
    u64* rowmask = (u64*)p;              size_t rb = (size_t)BN * QN * 4 * 8; p += rb;  // 2 MiB
    int* colcnt = (int*)p;               p += (size_t)BN * GN * 4;             // 16 KiB
    int* fbCount = (int*)p;              p += 64;
    int* rowcnt = (int*)p;               p += (size_t)BN * QN * 4;             // 256 KiB
    // ---- end zero region ----
    float* candcv = (float*)p;           p += (size_t)BN * GN * 5 * 4;         // 80 KiB
    int* candci = (int*)p;               p += (size_t)BN * GN * 5 * 4;         // 80 KiB
    int* dkArr = (int*)p;                p += (size_t)BN * GN * 4;             // 16 KiB
    u64* amin = (u64*)p;                 p += (size_t)BN * GN * 8;             // 32 KiB
    u64* staleAmin = (u64*)p;            p += (size_t)BN * GN * 8;             // 32 KiB (init in k_dk)
    int* fbL = (int*)p;                  p += (size_t)BN * GN * 4;             // 16 KiB

    // zero region size in u64: rowmask(2MiB) + colcnt(16KiB) + 64B + rowcnt(256KiB)
    int zn = (int)((rb + (size_t)BN * GN * 4 + 64 + (size_t)BN * QN * 4) / 8);  // = 296968

    k_main<<<BN * NPART, 256, 0, stream>>>(logits, labels, gtb, gtt, gtr, imgt,
                                           pboxes, pposes, img, costT, rec,
                                           (u64*)rowmask, zn);
    k_dk<<<BN * GN / 4, 256, 0, stream>>>(rec, candcv, candci, dkArr, rowmask, amin, rowcnt,
                                          staleAmin);
    k_fix5<<<256 + BN, 256, 0, stream>>>(costT, rowmask, colcnt, rowcnt, candcv, candci,
                                         amin, staleAmin, fbCount, fbL);
    k_fba<<<BN + 256, 256, 0, stream>>>(costT, rowcnt, colcnt, amin, fbCount, fbL,
                                        candcv, candci, dkArr, staleAmin, rowmask, out);
    k_out<<<256, 256, 0, stream>>>(rowmask, out);
}